// Round 12
// baseline (470.928 us; speedup 1.0000x reference)
//
#include <hip/hip_runtime.h>
#include <hip/hip_bf16.h>

#define DEV __device__ __forceinline__

typedef __attribute__((ext_vector_type(8))) short bf16x8;
typedef __attribute__((ext_vector_type(4))) short s16x4;
typedef __attribute__((ext_vector_type(4))) float f32x4;

constexpr int B_ = 2, S_ = 2048, HID_ = 4096, NH_ = 32, NKV_ = 8, D_ = 128;
constexpr int GROUPS_ = NH_ / NKV_;
// fold 1/sqrt(D) and log2(e) into Q so attention uses exp2 directly
constexpr float QSCALE_ = 0.08838834764831845f * 1.4426950408889634f;

DEV unsigned short f2bf(float x) {
    union { float f; unsigned int u; } v; v.f = x;
    unsigned int r = v.u + 0x7fffu + ((v.u >> 16) & 1u);
    return (unsigned short)(r >> 16);
}

DEV f32x4 mfma16(bf16x8 a, bf16x8 b, f32x4 c) {
    return __builtin_amdgcn_mfma_f32_16x16x32_bf16(a, b, c, 0, 0, 0);
}

DEV void gll16(const void* g, void* l) {
    __builtin_amdgcn_global_load_lds(
        (const __attribute__((address_space(1))) unsigned int*)g,
        (__attribute__((address_space(3))) unsigned int*)l, 16, 0, 0);
}

// pi: permute s within 32-blocks so attn V b128 reads match the sigma k-slot
// mapping (sigma per 32-kv block: pos lb*8+m*4+r holds kv m*16+lb*4+r).
// 4-aligned-preserving: pi(s) = (s&~31)|((s>>2)&3)<<3|((s>>4)&1)<<2|(s&3)
DEV int vperm(int s) {
    return (s & ~31) | (((s >> 2) & 3) << 3) | (((s >> 4) & 1) << 2) | (s & 3);
}

// ---------------- merged fp32 -> bf16 cast (one launch, 5 segments) ----------
__global__ __launch_bounds__(256) void cast_all_k(
    const float* __restrict__ s0, const float* __restrict__ s1,
    const float* __restrict__ s2, const float* __restrict__ s3,
    const float* __restrict__ s4,
    unsigned short* __restrict__ d0, unsigned short* __restrict__ d1,
    unsigned short* __restrict__ d2, unsigned short* __restrict__ d3,
    unsigned short* __restrict__ d4)
{
    int bb = blockIdx.x;
    const float* s; unsigned short* d; int off;
    if      (bb < 8192)  { s = s0; d = d0; off = bb; }
    else if (bb < 16384) { s = s1; d = d1; off = bb - 8192; }
    else if (bb < 18432) { s = s2; d = d2; off = bb - 16384; }
    else if (bb < 20480) { s = s3; d = d3; off = bb - 18432; }
    else                 { s = s4; d = d4; off = bb - 20480; }
    size_t i = ((size_t)off * 256 + threadIdx.x) * 8;
    const f32x4* sp = (const f32x4*)(s + i);
    f32x4 a = sp[0], b = sp[1];
    bf16x8 o;
    o[0] = (short)f2bf(a[0]); o[1] = (short)f2bf(a[1]);
    o[2] = (short)f2bf(a[2]); o[3] = (short)f2bf(a[3]);
    o[4] = (short)f2bf(b[0]); o[5] = (short)f2bf(b[1]);
    o[6] = (short)f2bf(b[2]); o[7] = (short)f2bf(b[3]);
    *(bf16x8*)(d + i) = o;
}

// =============== 256x256 8-phase bf16 GEMM (T2+T3+T4+T5), C = A @ B^T ========
// EPI 0: f32 row-major store. EPI 1: Q RoPE epilogue (N=4096 launch).
// vmcnt ledger in INSTRUCTION units (each STAGE = 2 loads): prologue 8.
// P0 vmcnt(2) -> c0,c1,c2 complete; P2 vmcnt(4) -> c3 complete. Barriers only
// at P0/P2 (r9-proven: buf[nb] reads finished in tile t-1, ordered by P0).
template<int EPI>
__global__ __launch_bounds__(512, 2) void gemm256_k(
    const unsigned short* __restrict__ A, const unsigned short* __restrict__ Bw,
    float* __restrict__ Cf, unsigned short* __restrict__ Qo,
    const float* __restrict__ cosT, const float* __restrict__ sinT,
    int M, int N, int K)
{
    __shared__ __align__(16) unsigned short lds[65536];  // 128 KiB
    const int tid = threadIdx.x, lane = tid & 63;
    const int w = tid >> 6, wm = w >> 2, wn = w & 3;
    const int la = lane & 15, lb = lane >> 4;

    const int nwg = (int)gridDim.x;
    const int cpx = nwg >> 3;
    const int bid = (int)blockIdx.x;
    const int sw = (bid & 7) * cpx + (bid >> 3);
    const int ntn = N >> 8;
    const int bm = (sw / ntn) << 8, bn = (sw % ntn) << 8;

    const int srow = tid >> 3;                       // 0..63
    const int scol8 = (tid & 7) ^ (srow & 7);        // involution
    const size_t rK = (size_t)K;
    const unsigned short* gA = A + (size_t)(bm + srow) * rK + scol8 * 8;
    const unsigned short* gB = Bw + (size_t)(bn + srow) * rK + scol8 * 8;

#define STAGE_A_H0(buf, kt) { gll16(gA + (size_t)(kt),            &lds[(buf)*16384 + tid*8]); \
                              gll16(gA + (size_t)(kt) + 128*rK,   &lds[(buf)*16384 + 8192 + tid*8]); }
#define STAGE_A_H1(buf, kt) { gll16(gA + (size_t)(kt) + 64*rK,    &lds[(buf)*16384 + 4096 + tid*8]); \
                              gll16(gA + (size_t)(kt) + 192*rK,   &lds[(buf)*16384 + 12288 + tid*8]); }
#define STAGE_B_H0(buf, kt) { gll16(gB + (size_t)(kt),            &lds[32768 + (buf)*16384 + tid*8]); \
                              gll16(gB + (size_t)(kt) + 64*rK,    &lds[32768 + (buf)*16384 + 4096 + tid*8]); }
#define STAGE_B_H1(buf, kt) { gll16(gB + (size_t)(kt) + 128*rK,   &lds[32768 + (buf)*16384 + 8192 + tid*8]); \
                              gll16(gB + (size_t)(kt) + 192*rK,   &lds[32768 + (buf)*16384 + 12288 + tid*8]); }
#define SB0() __builtin_amdgcn_sched_barrier(0)

    f32x4 acc[8][4];
#pragma unroll
    for (int m = 0; m < 8; ++m)
#pragma unroll
        for (int j = 0; j < 4; ++j) acc[m][j] = f32x4{0.f, 0.f, 0.f, 0.f};

    auto rdA = [&](int buf, int m, int kk) -> bf16x8 {
        int r = wm * 128 + m * 16 + la;
        int slot = (kk * 4 + lb) ^ (la & 7);
        return *(const bf16x8*)&lds[buf * 16384 + r * 64 + slot * 8];
    };
    auto rdB = [&](int buf, int j, int kk) -> bf16x8 {
        int r = (wn + 4 * j) * 16 + la;
        int slot = (kk * 4 + lb) ^ (la & 7);
        return *(const bf16x8*)&lds[32768 + buf * 16384 + r * 64 + slot * 8];
    };

    STAGE_A_H0(0, 0); STAGE_B_H0(0, 0); STAGE_B_H1(0, 0); STAGE_A_H1(0, 0);

    bf16x8 af[4][2], b01[2][2], b23[2][2];
    int cur = 0;
    const int nt = K >> 6;
    for (int t = 0; t < nt; ++t) {
        const bool pre = (t + 1 < nt);
        const int kn = (t + 1) << 6;
        const int nb = cur ^ 1;
        // ---- P0: needs c0,c1 (vmcnt(2) confirms c0,c1,c2); barrier ----
        asm volatile("s_waitcnt vmcnt(2)" ::: "memory");
        SB0(); __builtin_amdgcn_s_barrier(); SB0();
#pragma unroll
        for (int m = 0; m < 4; ++m)
#pragma unroll
            for (int kk = 0; kk < 2; ++kk) af[m][kk] = rdA(cur, m, kk);
#pragma unroll
        for (int j = 0; j < 2; ++j)
#pragma unroll
            for (int kk = 0; kk < 2; ++kk) b01[j][kk] = rdB(cur, j, kk);
        if (pre) STAGE_A_H0(nb, kn);
        __builtin_amdgcn_s_setprio(1);
#pragma unroll
        for (int kk = 0; kk < 2; ++kk)
#pragma unroll
            for (int m = 0; m < 4; ++m)
#pragma unroll
                for (int j = 0; j < 2; ++j)
                    acc[m][j] = mfma16(af[m][kk], b01[j][kk], acc[m][j]);
        __builtin_amdgcn_s_setprio(0);
        // ---- P1: reads c2 (confirmed at P0); NO barrier needed ----
#pragma unroll
        for (int j = 0; j < 2; ++j)
#pragma unroll
            for (int kk = 0; kk < 2; ++kk) b23[j][kk] = rdB(cur, j + 2, kk);
        if (pre) STAGE_B_H0(nb, kn);
        __builtin_amdgcn_s_setprio(1);
#pragma unroll
        for (int kk = 0; kk < 2; ++kk)
#pragma unroll
            for (int m = 0; m < 4; ++m)
#pragma unroll
                for (int j = 0; j < 2; ++j)
                    acc[m][j + 2] = mfma16(af[m][kk], b23[j][kk], acc[m][j + 2]);
        __builtin_amdgcn_s_setprio(0);
        // ---- P2: needs c3 -> vmcnt(4) (c0',c1' remain); barrier ----
        if (pre) { asm volatile("s_waitcnt vmcnt(4)" ::: "memory"); }
        else     { asm volatile("s_waitcnt vmcnt(0)" ::: "memory"); }
        SB0(); __builtin_amdgcn_s_barrier(); SB0();
#pragma unroll
        for (int m = 0; m < 4; ++m)
#pragma unroll
            for (int kk = 0; kk < 2; ++kk) af[m][kk] = rdA(cur, m + 4, kk);
        if (pre) STAGE_B_H1(nb, kn);
        __builtin_amdgcn_s_setprio(1);
#pragma unroll
        for (int kk = 0; kk < 2; ++kk)
#pragma unroll
            for (int m = 0; m < 4; ++m)
#pragma unroll
                for (int j = 0; j < 2; ++j)
                    acc[m + 4][j + 2] = mfma16(af[m][kk], b23[j][kk], acc[m + 4][j + 2]);
        __builtin_amdgcn_s_setprio(0);
        // ---- P3: register-only MFMA; NO barrier needed ----
        if (pre) STAGE_A_H1(nb, kn);
        __builtin_amdgcn_s_setprio(1);
#pragma unroll
        for (int kk = 0; kk < 2; ++kk)
#pragma unroll
            for (int m = 0; m < 4; ++m)
#pragma unroll
                for (int j = 0; j < 2; ++j)
                    acc[m + 4][j] = mfma16(af[m][kk], b01[j][kk], acc[m + 4][j]);
        __builtin_amdgcn_s_setprio(0);
        cur ^= 1;
    }
#undef STAGE_A_H0
#undef STAGE_A_H1
#undef STAGE_B_H0
#undef STAGE_B_H1

    const int srow0 = bm + wm * 128;
    if constexpr (EPI == 0) {
#pragma unroll
        for (int m = 0; m < 8; ++m)
#pragma unroll
            for (int j = 0; j < 4; ++j) {
                int col = bn + (wn + 4 * j) * 16 + la;
#pragma unroll
                for (int r = 0; r < 4; ++r)
                    Cf[(size_t)(srow0 + m * 16 + lb * 4 + r) * N + col] = acc[m][j][r];
            }
    } else {
        // Q RoPE: j0/j1 = head hbase, j2/j3 = head hbase+1
        const int hbase = bn >> 7;
        const int d = wn * 16 + la;  // < 64; cos[d]==cos[d+64]
#pragma unroll
        for (int m = 0; m < 8; ++m) {
#pragma unroll
            for (int r = 0; r < 4; ++r) {
                int row = srow0 + m * 16 + lb * 4 + r;  // = b*S + s
                float cv = cosT[(size_t)row * D_ + d];
                float sv = sinT[(size_t)row * D_ + d];
#pragma unroll
                for (int p = 0; p < 2; ++p) {
                    float x1 = acc[m][p * 2 + 0][r], x2 = acc[m][p * 2 + 1][r];
                    unsigned short* o = Qo + (size_t)row * (NH_ * D_) + (hbase + p) * D_ + d;
                    o[0]  = f2bf((x1 * cv - x2 * sv) * QSCALE_);
                    o[64] = f2bf((x2 * cv + x1 * sv) * QSCALE_);
                }
            }
        }
    }
}

// =============== 128x128 2-phase bf16 GEMM for fused K+V (N=2048) ============
__global__ __launch_bounds__(512, 4) void gemm_kv_k(
    const unsigned short* __restrict__ A, const unsigned short* __restrict__ Bw,
    unsigned short* __restrict__ Ko, unsigned short* __restrict__ Vo,
    const float* __restrict__ cosT, const float* __restrict__ sinT,
    int M, int K)
{
    __shared__ __align__(16) unsigned short lds[32768];  // 64 KiB
    const int tid = threadIdx.x, lane = tid & 63;
    const int w = tid >> 6, wm = w >> 2, wn = w & 3;
    const int la = lane & 15, lb = lane >> 4;

    const int nwg = (int)gridDim.x;           // 512
    const int cpx = nwg >> 3;
    const int bid = (int)blockIdx.x;
    const int sw = (bid & 7) * cpx + (bid >> 3);
    const int ntn = 2048 >> 7;                // 16
    const int bm = (sw / ntn) << 7, bn = (sw % ntn) << 7;

    const int srow = tid >> 3;
    const int scol8 = (tid & 7) ^ (srow & 7);
    const size_t rK = (size_t)K;
    const unsigned short* gA = A + (size_t)(bm + srow) * rK + scol8 * 8;
    const unsigned short* gB = Bw + (size_t)(bn + srow) * rK + scol8 * 8;

#define KV_STG_A(buf, kt)  { gll16(gA + (size_t)(kt),          &lds[(buf)*8192 + tid*8]); \
                             gll16(gA + (size_t)(kt) + 64*rK,  &lds[(buf)*8192 + 4096 + tid*8]); }
#define KV_STG_B0(buf, kt)   gll16(gB + (size_t)(kt),          &lds[16384 + (buf)*8192 + tid*8])
#define KV_STG_B1(buf, kt)   gll16(gB + (size_t)(kt) + 64*rK,  &lds[16384 + (buf)*8192 + 4096 + tid*8])
#define SB0() __builtin_amdgcn_sched_barrier(0)

    f32x4 acc[4][2];
#pragma unroll
    for (int m = 0; m < 4; ++m)
#pragma unroll
        for (int j = 0; j < 2; ++j) acc[m][j] = f32x4{0.f, 0.f, 0.f, 0.f};

    auto rdA = [&](int buf, int m, int kk) -> bf16x8 {
        int r = wm * 64 + m * 16 + la;
        int slot = (kk * 4 + lb) ^ (la & 7);
        return *(const bf16x8*)&lds[buf * 8192 + r * 64 + slot * 8];
    };
    auto rdB = [&](int buf, int j, int kk) -> bf16x8 {
        int r = (wn + 4 * j) * 16 + la;
        int slot = (kk * 4 + lb) ^ (la & 7);
        return *(const bf16x8*)&lds[16384 + buf * 8192 + r * 64 + slot * 8];
    };

    KV_STG_A(0, 0); KV_STG_B0(0, 0); KV_STG_B1(0, 0);

    bf16x8 af[4][2], bf0[2], bf1[2];
    int cur = 0;
    const int nt = K >> 6;
    for (int t = 0; t < nt; ++t) {
        const bool pre = (t + 1 < nt);
        const int kn = (t + 1) << 6;
        const int nb = cur ^ 1;
        asm volatile("s_waitcnt vmcnt(1)" ::: "memory");
        SB0(); __builtin_amdgcn_s_barrier(); SB0();
#pragma unroll
        for (int m = 0; m < 4; ++m)
#pragma unroll
            for (int kk = 0; kk < 2; ++kk) af[m][kk] = rdA(cur, m, kk);
#pragma unroll
        for (int kk = 0; kk < 2; ++kk) bf0[kk] = rdB(cur, 0, kk);
        if (pre) { KV_STG_A(nb, kn); KV_STG_B0(nb, kn); }
        __builtin_amdgcn_s_setprio(1);
#pragma unroll
        for (int kk = 0; kk < 2; ++kk)
#pragma unroll
            for (int m = 0; m < 4; ++m)
                acc[m][0] = mfma16(af[m][kk], bf0[kk], acc[m][0]);
        __builtin_amdgcn_s_setprio(0);
        if (pre) { asm volatile("s_waitcnt vmcnt(3)" ::: "memory"); }
        else     { asm volatile("s_waitcnt vmcnt(0)" ::: "memory"); }
        SB0(); __builtin_amdgcn_s_barrier(); SB0();
#pragma unroll
        for (int kk = 0; kk < 2; ++kk) bf1[kk] = rdB(cur, 1, kk);
        if (pre) KV_STG_B1(nb, kn);
        __builtin_amdgcn_s_setprio(1);
#pragma unroll
        for (int kk = 0; kk < 2; ++kk)
#pragma unroll
            for (int m = 0; m < 4; ++m)
                acc[m][1] = mfma16(af[m][kk], bf1[kk], acc[m][1]);
        __builtin_amdgcn_s_setprio(0);
        cur ^= 1;
    }
#undef KV_STG_A
#undef KV_STG_B0
#undef KV_STG_B1
#undef SB0

    const int rbase = bm + wm * 64;
    if (bn < 1024) {
        const int hbase = bn >> 7;
        const int d = wn * 16 + la;  // < 64
#pragma unroll
        for (int m = 0; m < 4; ++m)
#pragma unroll
            for (int r = 0; r < 4; ++r) {
                int row = rbase + m * 16 + lb * 4 + r;  // = b*S + s
                float cv = cosT[(size_t)row * D_ + d];
                float sv = sinT[(size_t)row * D_ + d];
                float x1 = acc[m][0][r], x2 = acc[m][1][r];
                unsigned short* o = Ko + (size_t)row * (NKV_ * D_) + hbase * D_ + d;
                o[0]  = f2bf(x1 * cv - x2 * sv);
                o[64] = f2bf(x2 * cv + x1 * sv);
            }
    } else {
        // V^T (B,NKV,D,S) with pi-permuted S (4-aligned rows: s%4==0)
        const int kv = (bn - 1024) >> 7;
#pragma unroll
        for (int m = 0; m < 4; ++m) {
            int row = rbase + m * 16 + lb * 4;
            int b = row >> 11, s = row & (S_ - 1);
            int sp = vperm(s);
#pragma unroll
            for (int j = 0; j < 2; ++j) {
                int d = (wn + 4 * j) * 16 + la;
                s16x4 pk;
#pragma unroll
                for (int r = 0; r < 4; ++r) pk[r] = (short)f2bf(acc[m][j][r]);
                *(s16x4*)&Vo[((size_t)(b * NKV_ + kv) * D_ + d) * S_ + sp] = pk;
            }
        }
    }
}

// ---------------- legacy fp32-input GEMM (ws fallback) -----------------------
template<int EPI, bool ABF16>
__global__ __launch_bounds__(256) void gemm_legacy_k(
    const void* __restrict__ Ap, const float* __restrict__ Bp,
    void* __restrict__ Cp, const float* __restrict__ cosT,
    const float* __restrict__ sinT, int M, int N, int K, float scale)
{
    constexpr int LDT = 40;
    __shared__ __align__(16) unsigned short Asm[128 * LDT];
    __shared__ __align__(16) unsigned short Bsm[128 * LDT];
    const int tid = threadIdx.x;
    const int lane = tid & 63;
    const int w = tid >> 6;
    const int la = lane & 15, lb = lane >> 4;
    const int ntn = N >> 7;
    const int bm = (int)(blockIdx.x / ntn) << 7;
    const int bn = (int)(blockIdx.x % ntn) << 7;

    f32x4 acc[2][8];
#pragma unroll
    for (int i = 0; i < 2; ++i)
#pragma unroll
        for (int j = 0; j < 8; ++j) acc[i][j] = f32x4{0.f, 0.f, 0.f, 0.f};

    for (int kt = 0; kt < K; kt += 32) {
        if constexpr (!ABF16) {
#pragma unroll
            for (int it = 0; it < 4; ++it) {
                int idx = it * 256 + tid;
                int r = idx >> 3, c = (idx & 7) << 2;
                const float* g = (const float*)Ap + (size_t)(bm + r) * K + kt + c;
                f32x4 v = *(const f32x4*)g;
                union { unsigned long long q; unsigned short u[4]; } pk;
                pk.u[0] = f2bf(v[0]); pk.u[1] = f2bf(v[1]);
                pk.u[2] = f2bf(v[2]); pk.u[3] = f2bf(v[3]);
                *(unsigned long long*)&Asm[r * LDT + c] = pk.q;
            }
        } else {
#pragma unroll
            for (int it = 0; it < 2; ++it) {
                int idx = it * 256 + tid;
                int r = idx >> 2, c = (idx & 3) << 3;
                const unsigned short* g =
                    (const unsigned short*)Ap + (size_t)(bm + r) * K + kt + c;
                *(bf16x8*)&Asm[r * LDT + c] = *(const bf16x8*)g;
            }
        }
#pragma unroll
        for (int it = 0; it < 4; ++it) {
            int idx = it * 256 + tid;
            int r = idx >> 3, c = (idx & 7) << 2;
            const float* g = Bp + (size_t)(bn + r) * K + kt + c;
            f32x4 v = *(const f32x4*)g;
            union { unsigned long long q; unsigned short u[4]; } pk;
            pk.u[0] = f2bf(v[0]); pk.u[1] = f2bf(v[1]);
            pk.u[2] = f2bf(v[2]); pk.u[3] = f2bf(v[3]);
            *(unsigned long long*)&Bsm[r * LDT + c] = pk.q;
        }
        __syncthreads();
        bf16x8 af0 = *(bf16x8*)&Asm[(w * 32 + la) * LDT + lb * 8];
        bf16x8 af1 = *(bf16x8*)&Asm[(w * 32 + 16 + la) * LDT + lb * 8];
#pragma unroll
        for (int nb = 0; nb < 8; ++nb) {
            bf16x8 bfr = *(bf16x8*)&Bsm[(nb * 16 + la) * LDT + lb * 8];
            acc[0][nb] = mfma16(af0, bfr, acc[0][nb]);
            acc[1][nb] = mfma16(af1, bfr, acc[1][nb]);
        }
        __syncthreads();
    }

    const int rbase = bm + w * 32;
    if constexpr (EPI == 0) {
        float* C = (float*)Cp;
#pragma unroll
        for (int mf = 0; mf < 2; ++mf)
#pragma unroll
            for (int nb = 0; nb < 8; ++nb)
#pragma unroll
                for (int r = 0; r < 4; ++r)
                    C[(size_t)(rbase + mf * 16 + lb * 4 + r) * N + bn + nb * 16 + la] =
                        acc[mf][nb][r];
    } else if constexpr (EPI == 1) {
        unsigned short* C = (unsigned short*)Cp;
#pragma unroll
        for (int mf = 0; mf < 2; ++mf) {
#pragma unroll
            for (int r = 0; r < 4; ++r) {
                int m = rbase + mf * 16 + lb * 4 + r;
                const float* cb = cosT + (size_t)m * D_;
                const float* sb = sinT + (size_t)m * D_;
#pragma unroll
                for (int nb = 0; nb < 4; ++nb) {
                    int d = nb * 16 + la;
                    float c = cb[d], s = sb[d];
                    float x1 = acc[mf][nb][r], x2 = acc[mf][nb + 4][r];
                    C[(size_t)m * N + bn + d]      = f2bf((x1 * c - x2 * s) * scale);
                    C[(size_t)m * N + bn + d + 64] = f2bf((x2 * c + x1 * s) * scale);
                }
            }
        }
    } else {
        unsigned short* C = (unsigned short*)Cp;
#pragma unroll
        for (int mf = 0; mf < 2; ++mf)
#pragma unroll
            for (int nb = 0; nb < 8; ++nb)
#pragma unroll
                for (int r = 0; r < 4; ++r) {
                    int m = rbase + mf * 16 + lb * 4 + r;
                    int b = m >> 11, s = m & (S_ - 1);
                    int n = bn + nb * 16 + la;
                    int kv = n >> 7, d = n & 127;
                    C[(((size_t)b * NKV_ + kv) * D_ + d) * S_ + vperm(s)] =
                        f2bf(acc[mf][nb][r]);
                }
    }
}

// ========== flash attention v8: 16 q-rows/wave, 64 q/block, 2048 blocks ======
// 4 waves x 16 q-rows = 64 q/block. KVBLK=32, 32 KiB dbuf LDS. Halved per-wave
// state (VGPR ~70) + 2x blocks -> more resident waves to hide the VALU-bound
// softmax (r11: MfmaUtil 25 + VALUBusy 53 at occ 27%). Same (256,2) bounds,
// same staging/sigma/pi layouts as r11-proven attn7 (mq extent 2 -> 1).
__global__ __launch_bounds__(256, 2) void attn8_k(
    const unsigned short* __restrict__ Qw,  // (B,S,NH,D) bf16 * QSCALE
    const unsigned short* __restrict__ Kw,  // (B,S,NKV,D) bf16
    const unsigned short* __restrict__ Vt,  // (B,NKV,D,S-pi) bf16
    unsigned short* __restrict__ Ow)        // (B,S,NH*D) bf16
{
    __shared__ __align__(16) unsigned short Ksm[2][32 * 128];   // 2 x 8 KiB
    __shared__ __align__(16) unsigned short Vsm[2][64 * 64];    // 2 x 8 KiB
    const int tid = threadIdx.x, lane = tid & 63, w = tid >> 6;
    const int la = lane & 15, lb = lane >> 4;
    const int blk = blockIdx.x;
    const int g = blk >> 6;                        // 0..31
    const int qbi = (g < 16) ? (31 - g) : (g - 16);  // heavy/light pairing
    const int bh = blk & 63;
    const int b = bh >> 5, h = bh & 31;
    const int kvh = h >> 2;
    const int qb = qbi * 64;
    const int qw0 = qb + w * 16;

    bf16x8 fq[4];
    const unsigned short* qp =
        Qw + ((size_t)(b * S_ + qw0 + la) * NH_ + h) * D_ + lb * 8;
#pragma unroll
    for (int kc = 0; kc < 4; ++kc)
        fq[kc] = *(const bf16x8*)(qp + kc * 32);

    bf16x8 ones;
#pragma unroll
    for (int i = 0; i < 8; ++i) ones[i] = (short)0x3F80;  // bf16 1.0

    float m_ = -__builtin_inff();
    f32x4 oacc[8], lacc;
    lacc = f32x4{0.f, 0.f, 0.f, 0.f};
#pragma unroll
    for (int db = 0; db < 8; ++db) oacc[db] = f32x4{0.f, 0.f, 0.f, 0.f};

    // staging (256 threads): K = 2 gll (32x128), V = 2 gll ([64][64] tile)
    const int krb = tid >> 4, ksl = tid & 15;   // K: 16 rows/gll, 16 slots
    const int vrb = tid >> 3, vsl = tid & 7;    // V: 32 rows/gll, 8 slots
    const unsigned short* kbase = Kw + ((size_t)b * S_ * NKV_ + kvh) * D_;
    const unsigned short* vbase = Vt + ((size_t)(b * NKV_ + kvh) * D_) * S_;

#define STAGE_KV(buf, kv0) {                                                   \
    _Pragma("unroll")                                                          \
    for (int it = 0; it < 2; ++it) {                                           \
        int row = it * 16 + krb;                                               \
        int cc = ksl ^ (row & 7);                                              \
        gll16(kbase + (size_t)(kv0 + row) * NKV_ * D_ + cc * 8,                \
              &Ksm[buf][(it * 256 + tid) * 8]);                                \
    }                                                                          \
    _Pragma("unroll")                                                          \
    for (int it = 0; it < 2; ++it) {                                           \
        int row = it * 32 + vrb;                                               \
        int cc = vsl ^ (row & 7);                                              \
        int dg = ((cc >> 2) << 6) + row;                                       \
        gll16(vbase + (size_t)dg * S_ + (kv0) + (cc & 3) * 8,                  \
              &Vsm[buf][(it * 256 + tid) * 8]);                                \
    }                                                                          \
}
#define SB0() __builtin_amdgcn_sched_barrier(0)

    STAGE_KV(0, 0);
    int cur = 0;
    const int ntiles = (qb + 64) >> 5;
    for (int t = 0; t < ntiles; ++t) {
        const int kv0 = t << 5;
        const bool pre = (t + 1 < ntiles);
        if (pre) STAGE_KV(cur ^ 1, kv0 + 32);
        if (pre) { asm volatile("s_waitcnt vmcnt(4)" ::: "memory"); }
        else     { asm volatile("s_waitcnt vmcnt(0)" ::: "memory"); }
        SB0(); __builtin_amdgcn_s_barrier(); SB0();

        if (kv0 < qw0 + 16) {  // wave-uniform causal skip
            // ---- QK^T swapped: sacc[nk], nk over 2 16-row k-blocks
            f32x4 sacc[2];
            sacc[0] = f32x4{0.f, 0.f, 0.f, 0.f};
            sacc[1] = f32x4{0.f, 0.f, 0.f, 0.f};
#pragma unroll
            for (int kc = 0; kc < 4; ++kc) {
#pragma unroll
                for (int nk = 0; nk < 2; ++nk) {
                    int row = nk * 16 + la;
                    int slot = (kc * 4 + lb) ^ (la & 7);
                    bf16x8 fk = *(const bf16x8*)&Ksm[cur][row * 128 + slot * 8];
                    sacc[nk] = mfma16(fk, fq[kc], sacc[nk]);
                }
            }
            // ---- mask + row max (k = kv0+nk*16+lb*4+r, q = qw0+la)
            const bool diag = (kv0 + 31 > qw0);
            float pv[2][4];
            const int q = qw0 + la;
            float mx = -__builtin_inff();
#pragma unroll
            for (int nk = 0; nk < 2; ++nk)
#pragma unroll
                for (int r = 0; r < 4; ++r) {
                    float s = sacc[nk][r];
                    if (diag) {
                        int k = kv0 + nk * 16 + lb * 4 + r;
                        s = (k <= q) ? s : -__builtin_inff();
                    }
                    pv[nk][r] = s;
                    mx = fmaxf(mx, s);
                }
            mx = fmaxf(mx, __shfl_xor(mx, 16));
            mx = fmaxf(mx, __shfl_xor(mx, 32));
            // T13 defer-rescale (log2 domain, THR=8)
            const bool upd = __any(mx > m_ + 8.f);
            if (upd) {
                float mn = fmaxf(m_, mx);
                float fac = exp2f(m_ - mn);
                m_ = mn;
                lacc *= fac;
#pragma unroll
                for (int db = 0; db < 8; ++db) oacc[db] *= fac;
            }
#pragma unroll
            for (int nk = 0; nk < 2; ++nk)
#pragma unroll
                for (int r = 0; r < 4; ++r)
                    pv[nk][r] = exp2f(pv[nk][r] - m_);
            // ---- P fragment in-register (hw cvt_pk); K=32 -> single fragment
            union { bf16x8 v; __hip_bfloat162 h[4]; } fp;
            fp.h[0] = __float22bfloat162_rn(float2{pv[0][0], pv[0][1]});
            fp.h[1] = __float22bfloat162_rn(float2{pv[0][2], pv[0][3]});
            fp.h[2] = __float22bfloat162_rn(float2{pv[1][0], pv[1][1]});
            fp.h[3] = __float22bfloat162_rn(float2{pv[1][2], pv[1][3]});
            // ---- PV: V b128 from [64][64] tile; O^T += V*P; l += 1*P
#pragma unroll
            for (int db = 0; db < 8; ++db) {
                int r64 = (db & 3) * 16 + la;
                int slot = (((db >> 2) << 2) + lb) ^ (r64 & 7);
                bf16x8 fv = *(const bf16x8*)&Vsm[cur][r64 * 64 + slot * 8];
                oacc[db] = mfma16(fv, fp.v, oacc[db]);
            }
            lacc = mfma16(ones, fp.v, lacc);
        }
        SB0(); __builtin_amdgcn_s_barrier(); SB0();
        cur ^= 1;
    }
#undef STAGE_KV
#undef SB0

    // ---- normalize + store: d = db*16+lb*4+r, q = qw0+la
    {
        float rl = 1.f / lacc[0];
        int q = qw0 + la;
#pragma unroll
        for (int db = 0; db < 8; ++db) {
            f32x4 o = oacc[db];
            s16x4 pk;
#pragma unroll
            for (int r = 0; r < 4; ++r) pk[r] = (short)f2bf(o[r] * rl);
            int d = db * 16 + lb * 4;
            *(s16x4*)(Ow + (size_t)(b * S_ + q) * (NH_ * D_) + h * D_ + d) = pk;
        }
    }
}

extern "C" void kernel_launch(void* const* d_in, const int* in_sizes, int n_in,
                              void* d_out, int out_size, void* d_ws, size_t ws_size,
                              hipStream_t stream) {
    const float* hs   = (const float*)d_in[0];
    const float* cosT = (const float*)d_in[1];
    const float* sinT = (const float*)d_in[2];
    const float* Wq   = (const float*)d_in[3];
    const float* Wk   = (const float*)d_in[4];
    const float* Wv   = (const float*)d_in[5];
    const float* Wo   = (const float*)d_in[6];

    constexpr size_t Qn  = (size_t)B_ * S_ * NH_ * D_;    // 16.77M
    constexpr size_t Kn  = (size_t)B_ * S_ * NKV_ * D_;   // 4.19M
    constexpr size_t Hn  = (size_t)B_ * S_ * HID_;        // 16.77M
    constexpr size_t Wqn = (size_t)NH_ * D_ * HID_;       // 16.77M
    constexpr size_t Wkn = (size_t)NKV_ * D_ * HID_;      // 4.19M

    unsigned short* Qws   = (unsigned short*)d_ws;
    unsigned short* Kws   = Qws + Qn;
    unsigned short* Vtws  = Kws + Kn;
    unsigned short* AOws  = Vtws + Kn;
    unsigned short* hsb   = AOws + Qn;
    unsigned short* Wqkvb = hsb + Hn;                  // stacked (6144, 4096)
    unsigned short* Wob   = Wqkvb + Wqn + 2 * Wkn;
    constexpr size_t need = (Qn + 2 * Kn + Qn + Hn + Wqn + 2 * Wkn + Wqn) * 2;

    const int M = B_ * S_;
    dim3 blk(256);

    if (ws_size >= need) {
        // one merged cast launch: hs, Wq, Wk, Wv, Wo -> bf16
        cast_all_k<<<dim3(28672), blk, 0, stream>>>(
            hs, Wq, Wk, Wv, Wo,
            hsb, Wqkvb, Wqkvb + Wqn, Wqkvb + Wqn + Wkn, Wob);

        // Q = rope(hs @ Wq^T) * QSCALE  (grid 16x16 = 256, balanced)
        gemm256_k<1><<<dim3((M / 256) * (HID_ / 256)), dim3(512), 0, stream>>>(
            hsb, Wqkvb, nullptr, Qws, cosT, sinT, M, HID_, HID_);
        // K = rope(hs @ Wk^T), V^T(pi) = (hs @ Wv^T)^T  (grid 512 = 2/CU)
        gemm_kv_k<<<dim3((M / 128) * (2048 / 128)), dim3(512), 0, stream>>>(
            hsb, Wqkvb + Wqn, Kws, Vtws, cosT, sinT, M, HID_);
        // attention: 2048 blocks x 256 threads, 64 q-rows/block
        attn8_k<<<dim3(B_ * NH_ * (S_ / 64)), blk, 0, stream>>>(
            Qws, Kws, Vtws, AOws);
        // out = AO @ Wo^T (f32 epilogue)
        gemm256_k<0><<<dim3((M / 256) * (HID_ / 256)), dim3(512), 0, stream>>>(
            AOws, Wob, (float*)d_out, nullptr, nullptr, nullptr, M, HID_, NH_ * D_);
    } else {
        // fallback: fp32-staging GEMMs + attention
        unsigned short* Qf = (unsigned short*)d_ws;
        unsigned short* Kf = Qf + Qn;
        unsigned short* Vf = Kf + Kn;
        unsigned short* AOf = Vf + Kn;
        gemm_legacy_k<1, false><<<dim3((M / 128) * (NH_ * D_ / 128)), blk, 0, stream>>>(
            hs, Wq, Qf, cosT, sinT, M, NH_ * D_, HID_, QSCALE_);
        gemm_legacy_k<1, false><<<dim3((M / 128) * (NKV_ * D_ / 128)), blk, 0, stream>>>(
            hs, Wk, Kf, cosT, sinT, M, NKV_ * D_, HID_, 1.0f);
        gemm_legacy_k<3, false><<<dim3((M / 128) * (NKV_ * D_ / 128)), blk, 0, stream>>>(
            hs, Wv, Vf, nullptr, nullptr, M, NKV_ * D_, HID_, 0.f);
        attn8_k<<<dim3(B_ * NH_ * (S_ / 64)), blk, 0, stream>>>(
            Qf, Kf, Vf, AOf);
        gemm_legacy_k<0, true><<<dim3((M / 128) * (HID_ / 128)), blk, 0, stream>>>(
            AOf, Wo, (float*)d_out, nullptr, nullptr, M, HID_, NH_ * D_, 0.f);
    }
}

// Round 13
// 451.449 us; speedup vs baseline: 1.0431x; 1.0431x over previous
//
#include <hip/hip_runtime.h>
#include <hip/hip_bf16.h>

#define DEV __device__ __forceinline__

typedef __attribute__((ext_vector_type(8))) short bf16x8;
typedef __attribute__((ext_vector_type(4))) short s16x4;
typedef __attribute__((ext_vector_type(4))) float f32x4;

constexpr int B_ = 2, S_ = 2048, HID_ = 4096, NH_ = 32, NKV_ = 8, D_ = 128;
constexpr int GROUPS_ = NH_ / NKV_;
// fold 1/sqrt(D) and log2(e) into Q so attention uses exp2 directly
constexpr float QSCALE_ = 0.08838834764831845f * 1.4426950408889634f;

DEV unsigned short f2bf(float x) {
    union { float f; unsigned int u; } v; v.f = x;
    unsigned int r = v.u + 0x7fffu + ((v.u >> 16) & 1u);
    return (unsigned short)(r >> 16);
}

DEV f32x4 mfma16(bf16x8 a, bf16x8 b, f32x4 c) {
    return __builtin_amdgcn_mfma_f32_16x16x32_bf16(a, b, c, 0, 0, 0);
}

DEV void gll16(const void* g, void* l) {
    __builtin_amdgcn_global_load_lds(
        (const __attribute__((address_space(1))) unsigned int*)g,
        (__attribute__((address_space(3))) unsigned int*)l, 16, 0, 0);
}

// pi: permute s within 32-blocks so attn V b128 reads match the sigma k-slot
// mapping (sigma per 32-kv block: pos lb*8+m*4+r holds kv m*16+lb*4+r).
// 4-aligned-preserving: pi(s) = (s&~31)|((s>>2)&3)<<3|((s>>4)&1)<<2|(s&3)
DEV int vperm(int s) {
    return (s & ~31) | (((s >> 2) & 3) << 3) | (((s >> 4) & 1) << 2) | (s & 3);
}

// ---------------- merged fp32 -> bf16 cast (one launch, 5 segments) ----------
__global__ __launch_bounds__(256) void cast_all_k(
    const float* __restrict__ s0, const float* __restrict__ s1,
    const float* __restrict__ s2, const float* __restrict__ s3,
    const float* __restrict__ s4,
    unsigned short* __restrict__ d0, unsigned short* __restrict__ d1,
    unsigned short* __restrict__ d2, unsigned short* __restrict__ d3,
    unsigned short* __restrict__ d4)
{
    int bb = blockIdx.x;
    const float* s; unsigned short* d; int off;
    if      (bb < 8192)  { s = s0; d = d0; off = bb; }
    else if (bb < 16384) { s = s1; d = d1; off = bb - 8192; }
    else if (bb < 18432) { s = s2; d = d2; off = bb - 16384; }
    else if (bb < 20480) { s = s3; d = d3; off = bb - 18432; }
    else                 { s = s4; d = d4; off = bb - 20480; }
    size_t i = ((size_t)off * 256 + threadIdx.x) * 8;
    const f32x4* sp = (const f32x4*)(s + i);
    f32x4 a = sp[0], b = sp[1];
    bf16x8 o;
    o[0] = (short)f2bf(a[0]); o[1] = (short)f2bf(a[1]);
    o[2] = (short)f2bf(a[2]); o[3] = (short)f2bf(a[3]);
    o[4] = (short)f2bf(b[0]); o[5] = (short)f2bf(b[1]);
    o[6] = (short)f2bf(b[2]); o[7] = (short)f2bf(b[3]);
    *(bf16x8*)(d + i) = o;
}

// =============== 256x256 8-phase bf16 GEMM (T2+T3+T4+T5), C = A @ B^T ========
// EPI 0: f32 row-major store. EPI 1: Q RoPE epilogue (N=4096 launch).
// vmcnt ledger in INSTRUCTION units (each STAGE = 2 loads): prologue 8.
// P0 vmcnt(2) -> c0,c1,c2 complete; P2 vmcnt(4) -> c3 complete. Barriers only
// at P0/P2 (r9-proven: buf[nb] reads finished in tile t-1, ordered by P0).
template<int EPI>
__global__ __launch_bounds__(512, 2) void gemm256_k(
    const unsigned short* __restrict__ A, const unsigned short* __restrict__ Bw,
    float* __restrict__ Cf, unsigned short* __restrict__ Qo,
    const float* __restrict__ cosT, const float* __restrict__ sinT,
    int M, int N, int K)
{
    __shared__ __align__(16) unsigned short lds[65536];  // 128 KiB
    const int tid = threadIdx.x, lane = tid & 63;
    const int w = tid >> 6, wm = w >> 2, wn = w & 3;
    const int la = lane & 15, lb = lane >> 4;

    const int nwg = (int)gridDim.x;
    const int cpx = nwg >> 3;
    const int bid = (int)blockIdx.x;
    const int sw = (bid & 7) * cpx + (bid >> 3);
    const int ntn = N >> 8;
    const int bm = (sw / ntn) << 8, bn = (sw % ntn) << 8;

    const int srow = tid >> 3;                       // 0..63
    const int scol8 = (tid & 7) ^ (srow & 7);        // involution
    const size_t rK = (size_t)K;
    const unsigned short* gA = A + (size_t)(bm + srow) * rK + scol8 * 8;
    const unsigned short* gB = Bw + (size_t)(bn + srow) * rK + scol8 * 8;

#define STAGE_A_H0(buf, kt) { gll16(gA + (size_t)(kt),            &lds[(buf)*16384 + tid*8]); \
                              gll16(gA + (size_t)(kt) + 128*rK,   &lds[(buf)*16384 + 8192 + tid*8]); }
#define STAGE_A_H1(buf, kt) { gll16(gA + (size_t)(kt) + 64*rK,    &lds[(buf)*16384 + 4096 + tid*8]); \
                              gll16(gA + (size_t)(kt) + 192*rK,   &lds[(buf)*16384 + 12288 + tid*8]); }
#define STAGE_B_H0(buf, kt) { gll16(gB + (size_t)(kt),            &lds[32768 + (buf)*16384 + tid*8]); \
                              gll16(gB + (size_t)(kt) + 64*rK,    &lds[32768 + (buf)*16384 + 4096 + tid*8]); }
#define STAGE_B_H1(buf, kt) { gll16(gB + (size_t)(kt) + 128*rK,   &lds[32768 + (buf)*16384 + 8192 + tid*8]); \
                              gll16(gB + (size_t)(kt) + 192*rK,   &lds[32768 + (buf)*16384 + 12288 + tid*8]); }
#define SB0() __builtin_amdgcn_sched_barrier(0)

    f32x4 acc[8][4];
#pragma unroll
    for (int m = 0; m < 8; ++m)
#pragma unroll
        for (int j = 0; j < 4; ++j) acc[m][j] = f32x4{0.f, 0.f, 0.f, 0.f};

    auto rdA = [&](int buf, int m, int kk) -> bf16x8 {
        int r = wm * 128 + m * 16 + la;
        int slot = (kk * 4 + lb) ^ (la & 7);
        return *(const bf16x8*)&lds[buf * 16384 + r * 64 + slot * 8];
    };
    auto rdB = [&](int buf, int j, int kk) -> bf16x8 {
        int r = (wn + 4 * j) * 16 + la;
        int slot = (kk * 4 + lb) ^ (la & 7);
        return *(const bf16x8*)&lds[32768 + buf * 16384 + r * 64 + slot * 8];
    };

    STAGE_A_H0(0, 0); STAGE_B_H0(0, 0); STAGE_B_H1(0, 0); STAGE_A_H1(0, 0);

    bf16x8 af[4][2], b01[2][2], b23[2][2];
    int cur = 0;
    const int nt = K >> 6;
    for (int t = 0; t < nt; ++t) {
        const bool pre = (t + 1 < nt);
        const int kn = (t + 1) << 6;
        const int nb = cur ^ 1;
        // ---- P0: needs c0,c1 (vmcnt(2) confirms c0,c1,c2); barrier ----
        asm volatile("s_waitcnt vmcnt(2)" ::: "memory");
        SB0(); __builtin_amdgcn_s_barrier(); SB0();
#pragma unroll
        for (int m = 0; m < 4; ++m)
#pragma unroll
            for (int kk = 0; kk < 2; ++kk) af[m][kk] = rdA(cur, m, kk);
#pragma unroll
        for (int j = 0; j < 2; ++j)
#pragma unroll
            for (int kk = 0; kk < 2; ++kk) b01[j][kk] = rdB(cur, j, kk);
        if (pre) STAGE_A_H0(nb, kn);
        __builtin_amdgcn_s_setprio(1);
#pragma unroll
        for (int kk = 0; kk < 2; ++kk)
#pragma unroll
            for (int m = 0; m < 4; ++m)
#pragma unroll
                for (int j = 0; j < 2; ++j)
                    acc[m][j] = mfma16(af[m][kk], b01[j][kk], acc[m][j]);
        __builtin_amdgcn_s_setprio(0);
        // ---- P1: reads c2 (confirmed at P0); NO barrier needed ----
#pragma unroll
        for (int j = 0; j < 2; ++j)
#pragma unroll
            for (int kk = 0; kk < 2; ++kk) b23[j][kk] = rdB(cur, j + 2, kk);
        if (pre) STAGE_B_H0(nb, kn);
        __builtin_amdgcn_s_setprio(1);
#pragma unroll
        for (int kk = 0; kk < 2; ++kk)
#pragma unroll
            for (int m = 0; m < 4; ++m)
#pragma unroll
                for (int j = 0; j < 2; ++j)
                    acc[m][j + 2] = mfma16(af[m][kk], b23[j][kk], acc[m][j + 2]);
        __builtin_amdgcn_s_setprio(0);
        // ---- P2: needs c3 -> vmcnt(4) (c0',c1' remain); barrier ----
        if (pre) { asm volatile("s_waitcnt vmcnt(4)" ::: "memory"); }
        else     { asm volatile("s_waitcnt vmcnt(0)" ::: "memory"); }
        SB0(); __builtin_amdgcn_s_barrier(); SB0();
#pragma unroll
        for (int m = 0; m < 4; ++m)
#pragma unroll
            for (int kk = 0; kk < 2; ++kk) af[m][kk] = rdA(cur, m + 4, kk);
        if (pre) STAGE_B_H1(nb, kn);
        __builtin_amdgcn_s_setprio(1);
#pragma unroll
        for (int kk = 0; kk < 2; ++kk)
#pragma unroll
            for (int m = 0; m < 4; ++m)
#pragma unroll
                for (int j = 0; j < 2; ++j)
                    acc[m + 4][j + 2] = mfma16(af[m][kk], b23[j][kk], acc[m + 4][j + 2]);
        __builtin_amdgcn_s_setprio(0);
        // ---- P3: register-only MFMA; NO barrier needed ----
        if (pre) STAGE_A_H1(nb, kn);
        __builtin_amdgcn_s_setprio(1);
#pragma unroll
        for (int kk = 0; kk < 2; ++kk)
#pragma unroll
            for (int m = 0; m < 4; ++m)
#pragma unroll
                for (int j = 0; j < 2; ++j)
                    acc[m + 4][j] = mfma16(af[m][kk], b01[j][kk], acc[m + 4][j]);
        __builtin_amdgcn_s_setprio(0);
        cur ^= 1;
    }
#undef STAGE_A_H0
#undef STAGE_A_H1
#undef STAGE_B_H0
#undef STAGE_B_H1

    const int srow0 = bm + wm * 128;
    if constexpr (EPI == 0) {
#pragma unroll
        for (int m = 0; m < 8; ++m)
#pragma unroll
            for (int j = 0; j < 4; ++j) {
                int col = bn + (wn + 4 * j) * 16 + la;
#pragma unroll
                for (int r = 0; r < 4; ++r)
                    Cf[(size_t)(srow0 + m * 16 + lb * 4 + r) * N + col] = acc[m][j][r];
            }
    } else {
        // Q RoPE: j0/j1 = head hbase, j2/j3 = head hbase+1
        const int hbase = bn >> 7;
        const int d = wn * 16 + la;  // < 64; cos[d]==cos[d+64]
#pragma unroll
        for (int m = 0; m < 8; ++m) {
#pragma unroll
            for (int r = 0; r < 4; ++r) {
                int row = srow0 + m * 16 + lb * 4 + r;  // = b*S + s
                float cv = cosT[(size_t)row * D_ + d];
                float sv = sinT[(size_t)row * D_ + d];
#pragma unroll
                for (int p = 0; p < 2; ++p) {
                    float x1 = acc[m][p * 2 + 0][r], x2 = acc[m][p * 2 + 1][r];
                    unsigned short* o = Qo + (size_t)row * (NH_ * D_) + (hbase + p) * D_ + d;
                    o[0]  = f2bf((x1 * cv - x2 * sv) * QSCALE_);
                    o[64] = f2bf((x2 * cv + x1 * sv) * QSCALE_);
                }
            }
        }
    }
}

// =============== 128x128 2-phase bf16 GEMM for fused K+V (N=2048) ============
__global__ __launch_bounds__(512, 4) void gemm_kv_k(
    const unsigned short* __restrict__ A, const unsigned short* __restrict__ Bw,
    unsigned short* __restrict__ Ko, unsigned short* __restrict__ Vo,
    const float* __restrict__ cosT, const float* __restrict__ sinT,
    int M, int K)
{
    __shared__ __align__(16) unsigned short lds[32768];  // 64 KiB
    const int tid = threadIdx.x, lane = tid & 63;
    const int w = tid >> 6, wm = w >> 2, wn = w & 3;
    const int la = lane & 15, lb = lane >> 4;

    const int nwg = (int)gridDim.x;           // 512
    const int cpx = nwg >> 3;
    const int bid = (int)blockIdx.x;
    const int sw = (bid & 7) * cpx + (bid >> 3);
    const int ntn = 2048 >> 7;                // 16
    const int bm = (sw / ntn) << 7, bn = (sw % ntn) << 7;

    const int srow = tid >> 3;
    const int scol8 = (tid & 7) ^ (srow & 7);
    const size_t rK = (size_t)K;
    const unsigned short* gA = A + (size_t)(bm + srow) * rK + scol8 * 8;
    const unsigned short* gB = Bw + (size_t)(bn + srow) * rK + scol8 * 8;

#define KV_STG_A(buf, kt)  { gll16(gA + (size_t)(kt),          &lds[(buf)*8192 + tid*8]); \
                             gll16(gA + (size_t)(kt) + 64*rK,  &lds[(buf)*8192 + 4096 + tid*8]); }
#define KV_STG_B0(buf, kt)   gll16(gB + (size_t)(kt),          &lds[16384 + (buf)*8192 + tid*8])
#define KV_STG_B1(buf, kt)   gll16(gB + (size_t)(kt) + 64*rK,  &lds[16384 + (buf)*8192 + 4096 + tid*8])
#define SB0() __builtin_amdgcn_sched_barrier(0)

    f32x4 acc[4][2];
#pragma unroll
    for (int m = 0; m < 4; ++m)
#pragma unroll
        for (int j = 0; j < 2; ++j) acc[m][j] = f32x4{0.f, 0.f, 0.f, 0.f};

    auto rdA = [&](int buf, int m, int kk) -> bf16x8 {
        int r = wm * 64 + m * 16 + la;
        int slot = (kk * 4 + lb) ^ (la & 7);
        return *(const bf16x8*)&lds[buf * 8192 + r * 64 + slot * 8];
    };
    auto rdB = [&](int buf, int j, int kk) -> bf16x8 {
        int r = (wn + 4 * j) * 16 + la;
        int slot = (kk * 4 + lb) ^ (la & 7);
        return *(const bf16x8*)&lds[16384 + buf * 8192 + r * 64 + slot * 8];
    };

    KV_STG_A(0, 0); KV_STG_B0(0, 0); KV_STG_B1(0, 0);

    bf16x8 af[4][2], bf0[2], bf1[2];
    int cur = 0;
    const int nt = K >> 6;
    for (int t = 0; t < nt; ++t) {
        const bool pre = (t + 1 < nt);
        const int kn = (t + 1) << 6;
        const int nb = cur ^ 1;
        asm volatile("s_waitcnt vmcnt(1)" ::: "memory");
        SB0(); __builtin_amdgcn_s_barrier(); SB0();
#pragma unroll
        for (int m = 0; m < 4; ++m)
#pragma unroll
            for (int kk = 0; kk < 2; ++kk) af[m][kk] = rdA(cur, m, kk);
#pragma unroll
        for (int kk = 0; kk < 2; ++kk) bf0[kk] = rdB(cur, 0, kk);
        if (pre) { KV_STG_A(nb, kn); KV_STG_B0(nb, kn); }
        __builtin_amdgcn_s_setprio(1);
#pragma unroll
        for (int kk = 0; kk < 2; ++kk)
#pragma unroll
            for (int m = 0; m < 4; ++m)
                acc[m][0] = mfma16(af[m][kk], bf0[kk], acc[m][0]);
        __builtin_amdgcn_s_setprio(0);
        if (pre) { asm volatile("s_waitcnt vmcnt(3)" ::: "memory"); }
        else     { asm volatile("s_waitcnt vmcnt(0)" ::: "memory"); }
        SB0(); __builtin_amdgcn_s_barrier(); SB0();
#pragma unroll
        for (int kk = 0; kk < 2; ++kk) bf1[kk] = rdB(cur, 1, kk);
        if (pre) KV_STG_B1(nb, kn);
        __builtin_amdgcn_s_setprio(1);
#pragma unroll
        for (int kk = 0; kk < 2; ++kk)
#pragma unroll
            for (int m = 0; m < 4; ++m)
                acc[m][1] = mfma16(af[m][kk], bf1[kk], acc[m][1]);
        __builtin_amdgcn_s_setprio(0);
        cur ^= 1;
    }
#undef KV_STG_A
#undef KV_STG_B0
#undef KV_STG_B1
#undef SB0

    const int rbase = bm + wm * 64;
    if (bn < 1024) {
        const int hbase = bn >> 7;
        const int d = wn * 16 + la;  // < 64
#pragma unroll
        for (int m = 0; m < 4; ++m)
#pragma unroll
            for (int r = 0; r < 4; ++r) {
                int row = rbase + m * 16 + lb * 4 + r;  // = b*S + s
                float cv = cosT[(size_t)row * D_ + d];
                float sv = sinT[(size_t)row * D_ + d];
                float x1 = acc[m][0][r], x2 = acc[m][1][r];
                unsigned short* o = Ko + (size_t)row * (NKV_ * D_) + hbase * D_ + d;
                o[0]  = f2bf(x1 * cv - x2 * sv);
                o[64] = f2bf(x2 * cv + x1 * sv);
            }
    } else {
        // V^T (B,NKV,D,S) with pi-permuted S (4-aligned rows: s%4==0)
        const int kv = (bn - 1024) >> 7;
#pragma unroll
        for (int m = 0; m < 4; ++m) {
            int row = rbase + m * 16 + lb * 4;
            int b = row >> 11, s = row & (S_ - 1);
            int sp = vperm(s);
#pragma unroll
            for (int j = 0; j < 2; ++j) {
                int d = (wn + 4 * j) * 16 + la;
                s16x4 pk;
#pragma unroll
                for (int r = 0; r < 4; ++r) pk[r] = (short)f2bf(acc[m][j][r]);
                *(s16x4*)&Vo[((size_t)(b * NKV_ + kv) * D_ + d) * S_ + sp] = pk;
            }
        }
    }
}

// ---------------- legacy fp32-input GEMM (ws fallback) -----------------------
template<int EPI, bool ABF16>
__global__ __launch_bounds__(256) void gemm_legacy_k(
    const void* __restrict__ Ap, const float* __restrict__ Bp,
    void* __restrict__ Cp, const float* __restrict__ cosT,
    const float* __restrict__ sinT, int M, int N, int K, float scale)
{
    constexpr int LDT = 40;
    __shared__ __align__(16) unsigned short Asm[128 * LDT];
    __shared__ __align__(16) unsigned short Bsm[128 * LDT];
    const int tid = threadIdx.x;
    const int lane = tid & 63;
    const int w = tid >> 6;
    const int la = lane & 15, lb = lane >> 4;
    const int ntn = N >> 7;
    const int bm = (int)(blockIdx.x / ntn) << 7;
    const int bn = (int)(blockIdx.x % ntn) << 7;

    f32x4 acc[2][8];
#pragma unroll
    for (int i = 0; i < 2; ++i)
#pragma unroll
        for (int j = 0; j < 8; ++j) acc[i][j] = f32x4{0.f, 0.f, 0.f, 0.f};

    for (int kt = 0; kt < K; kt += 32) {
        if constexpr (!ABF16) {
#pragma unroll
            for (int it = 0; it < 4; ++it) {
                int idx = it * 256 + tid;
                int r = idx >> 3, c = (idx & 7) << 2;
                const float* g = (const float*)Ap + (size_t)(bm + r) * K + kt + c;
                f32x4 v = *(const f32x4*)g;
                union { unsigned long long q; unsigned short u[4]; } pk;
                pk.u[0] = f2bf(v[0]); pk.u[1] = f2bf(v[1]);
                pk.u[2] = f2bf(v[2]); pk.u[3] = f2bf(v[3]);
                *(unsigned long long*)&Asm[r * LDT + c] = pk.q;
            }
        } else {
#pragma unroll
            for (int it = 0; it < 2; ++it) {
                int idx = it * 256 + tid;
                int r = idx >> 2, c = (idx & 3) << 3;
                const unsigned short* g =
                    (const unsigned short*)Ap + (size_t)(bm + r) * K + kt + c;
                *(bf16x8*)&Asm[r * LDT + c] = *(const bf16x8*)g;
            }
        }
#pragma unroll
        for (int it = 0; it < 4; ++it) {
            int idx = it * 256 + tid;
            int r = idx >> 3, c = (idx & 7) << 2;
            const float* g = Bp + (size_t)(bn + r) * K + kt + c;
            f32x4 v = *(const f32x4*)g;
            union { unsigned long long q; unsigned short u[4]; } pk;
            pk.u[0] = f2bf(v[0]); pk.u[1] = f2bf(v[1]);
            pk.u[2] = f2bf(v[2]); pk.u[3] = f2bf(v[3]);
            *(unsigned long long*)&Bsm[r * LDT + c] = pk.q;
        }
        __syncthreads();
        bf16x8 af0 = *(bf16x8*)&Asm[(w * 32 + la) * LDT + lb * 8];
        bf16x8 af1 = *(bf16x8*)&Asm[(w * 32 + 16 + la) * LDT + lb * 8];
#pragma unroll
        for (int nb = 0; nb < 8; ++nb) {
            bf16x8 bfr = *(bf16x8*)&Bsm[(nb * 16 + la) * LDT + lb * 8];
            acc[0][nb] = mfma16(af0, bfr, acc[0][nb]);
            acc[1][nb] = mfma16(af1, bfr, acc[1][nb]);
        }
        __syncthreads();
    }

    const int rbase = bm + w * 32;
    if constexpr (EPI == 0) {
        float* C = (float*)Cp;
#pragma unroll
        for (int mf = 0; mf < 2; ++mf)
#pragma unroll
            for (int nb = 0; nb < 8; ++nb)
#pragma unroll
                for (int r = 0; r < 4; ++r)
                    C[(size_t)(rbase + mf * 16 + lb * 4 + r) * N + bn + nb * 16 + la] =
                        acc[mf][nb][r];
    } else if constexpr (EPI == 1) {
        unsigned short* C = (unsigned short*)Cp;
#pragma unroll
        for (int mf = 0; mf < 2; ++mf) {
#pragma unroll
            for (int r = 0; r < 4; ++r) {
                int m = rbase + mf * 16 + lb * 4 + r;
                const float* cb = cosT + (size_t)m * D_;
                const float* sb = sinT + (size_t)m * D_;
#pragma unroll
                for (int nb = 0; nb < 4; ++nb) {
                    int d = nb * 16 + la;
                    float c = cb[d], s = sb[d];
                    float x1 = acc[mf][nb][r], x2 = acc[mf][nb + 4][r];
                    C[(size_t)m * N + bn + d]      = f2bf((x1 * c - x2 * s) * scale);
                    C[(size_t)m * N + bn + d + 64] = f2bf((x2 * c + x1 * s) * scale);
                }
            }
        }
    } else {
        unsigned short* C = (unsigned short*)Cp;
#pragma unroll
        for (int mf = 0; mf < 2; ++mf)
#pragma unroll
            for (int nb = 0; nb < 8; ++nb)
#pragma unroll
                for (int r = 0; r < 4; ++r) {
                    int m = rbase + mf * 16 + lb * 4 + r;
                    int b = m >> 11, s = m & (S_ - 1);
                    int n = bn + nb * 16 + la;
                    int kv = n >> 7, d = n & 127;
                    C[(((size_t)b * NKV_ + kv) * D_ + d) * S_ + vperm(s)] =
                        f2bf(acc[mf][nb][r]);
                }
    }
}

// ========== flash attention v7 (r11-proven) + T5 setprio =====================
// 4 waves x 32 q-rows = 128 q/block. KVBLK=32, 32 KiB dbuf LDS, (256,2) bounds
// (VGPR 84, no spill, 4 blocks/CU). V LDS [64][64], b128 XOR reads. The ONLY
// change vs r11: s_setprio(1)/(0) around the QK^T and PV MFMA clusters (T5:
// +4-7% attn, m191 — attn qualifies: independent blocks at different phases).
__global__ __launch_bounds__(256, 2) void attn7_k(
    const unsigned short* __restrict__ Qw,  // (B,S,NH,D) bf16 * QSCALE
    const unsigned short* __restrict__ Kw,  // (B,S,NKV,D) bf16
    const unsigned short* __restrict__ Vt,  // (B,NKV,D,S-pi) bf16
    unsigned short* __restrict__ Ow)        // (B,S,NH*D) bf16
{
    __shared__ __align__(16) unsigned short Ksm[2][32 * 128];   // 2 x 8 KiB
    __shared__ __align__(16) unsigned short Vsm[2][64 * 64];    // 2 x 8 KiB
    const int tid = threadIdx.x, lane = tid & 63, w = tid >> 6;
    const int la = lane & 15, lb = lane >> 4;
    const int blk = blockIdx.x;
    const int g = blk >> 6;                       // 0..15
    const int qbi = (g < 8) ? (15 - g) : (g - 8); // heavy/light pairing
    const int bh = blk & 63;
    const int b = bh >> 5, h = bh & 31;
    const int kvh = h >> 2;
    const int qb = qbi * 128;
    const int qw0 = qb + w * 32;

    bf16x8 fq[2][4];
    const unsigned short* qp =
        Qw + ((size_t)(b * S_ + qw0 + la) * NH_ + h) * D_ + lb * 8;
#pragma unroll
    for (int mq = 0; mq < 2; ++mq)
#pragma unroll
        for (int kc = 0; kc < 4; ++kc)
            fq[mq][kc] = *(const bf16x8*)(qp + (size_t)mq * 16 * NH_ * D_ + kc * 32);

    bf16x8 ones;
#pragma unroll
    for (int i = 0; i < 8; ++i) ones[i] = (short)0x3F80;  // bf16 1.0

    float m_[2];
    f32x4 oacc[8][2], lacc[2];
    m_[0] = m_[1] = -__builtin_inff();
    lacc[0] = lacc[1] = f32x4{0.f, 0.f, 0.f, 0.f};
#pragma unroll
    for (int db = 0; db < 8; ++db)
#pragma unroll
        for (int mq = 0; mq < 2; ++mq) oacc[db][mq] = f32x4{0.f, 0.f, 0.f, 0.f};

    // staging (256 threads): K = 2 gll (32x128), V = 2 gll ([64][64] tile)
    const int krb = tid >> 4, ksl = tid & 15;   // K: 16 rows/gll, 16 slots
    const int vrb = tid >> 3, vsl = tid & 7;    // V: 32 rows/gll, 8 slots
    const unsigned short* kbase = Kw + ((size_t)b * S_ * NKV_ + kvh) * D_;
    const unsigned short* vbase = Vt + ((size_t)(b * NKV_ + kvh) * D_) * S_;

#define STAGE_KV(buf, kv0) {                                                   \
    _Pragma("unroll")                                                          \
    for (int it = 0; it < 2; ++it) {                                           \
        int row = it * 16 + krb;                                               \
        int cc = ksl ^ (row & 7);                                              \
        gll16(kbase + (size_t)(kv0 + row) * NKV_ * D_ + cc * 8,                \
              &Ksm[buf][(it * 256 + tid) * 8]);                                \
    }                                                                          \
    _Pragma("unroll")                                                          \
    for (int it = 0; it < 2; ++it) {                                           \
        int row = it * 32 + vrb;                                               \
        int cc = vsl ^ (row & 7);                                              \
        int dg = ((cc >> 2) << 6) + row;                                       \
        gll16(vbase + (size_t)dg * S_ + (kv0) + (cc & 3) * 8,                  \
              &Vsm[buf][(it * 256 + tid) * 8]);                                \
    }                                                                          \
}
#define SB0() __builtin_amdgcn_sched_barrier(0)

    STAGE_KV(0, 0);
    int cur = 0;
    const int ntiles = (qb + 128) >> 5;
    for (int t = 0; t < ntiles; ++t) {
        const int kv0 = t << 5;
        const bool pre = (t + 1 < ntiles);
        if (pre) STAGE_KV(cur ^ 1, kv0 + 32);
        if (pre) { asm volatile("s_waitcnt vmcnt(4)" ::: "memory"); }
        else     { asm volatile("s_waitcnt vmcnt(0)" ::: "memory"); }
        SB0(); __builtin_amdgcn_s_barrier(); SB0();

        if (kv0 < qw0 + 32) {  // wave-uniform causal skip
            // ---- QK^T swapped: sacc[nk][mq], nk over 2 16-row k-blocks
            f32x4 sacc[2][2];
#pragma unroll
            for (int nk = 0; nk < 2; ++nk)
#pragma unroll
                for (int mq = 0; mq < 2; ++mq) sacc[nk][mq] = f32x4{0.f, 0.f, 0.f, 0.f};
            __builtin_amdgcn_s_setprio(1);
#pragma unroll
            for (int kc = 0; kc < 4; ++kc) {
#pragma unroll
                for (int nk = 0; nk < 2; ++nk) {
                    int row = nk * 16 + la;
                    int slot = (kc * 4 + lb) ^ (la & 7);
                    bf16x8 fk = *(const bf16x8*)&Ksm[cur][row * 128 + slot * 8];
#pragma unroll
                    for (int mq = 0; mq < 2; ++mq)
                        sacc[nk][mq] = mfma16(fk, fq[mq][kc], sacc[nk][mq]);
                }
            }
            __builtin_amdgcn_s_setprio(0);
            // ---- mask + row max (k = kv0+nk*16+lb*4+r, q = qw0+mq*16+la)
            const bool diag = (kv0 + 31 > qw0);
            float pv[2][2][4];
            float pm[2];
#pragma unroll
            for (int mq = 0; mq < 2; ++mq) {
                int q = qw0 + mq * 16 + la;
                float mx = -__builtin_inff();
#pragma unroll
                for (int nk = 0; nk < 2; ++nk)
#pragma unroll
                    for (int r = 0; r < 4; ++r) {
                        float s = sacc[nk][mq][r];
                        if (diag) {
                            int k = kv0 + nk * 16 + lb * 4 + r;
                            s = (k <= q) ? s : -__builtin_inff();
                        }
                        pv[nk][mq][r] = s;
                        mx = fmaxf(mx, s);
                    }
                mx = fmaxf(mx, __shfl_xor(mx, 16));
                mx = fmaxf(mx, __shfl_xor(mx, 32));
                pm[mq] = mx;
            }
            // T13 defer-rescale (log2 domain, THR=8)
            const bool upd =
                __any((pm[0] > m_[0] + 8.f) || (pm[1] > m_[1] + 8.f));
            if (upd) {
#pragma unroll
                for (int mq = 0; mq < 2; ++mq) {
                    float mn = fmaxf(m_[mq], pm[mq]);
                    float fac = exp2f(m_[mq] - mn);
                    m_[mq] = mn;
                    lacc[mq] *= fac;
#pragma unroll
                    for (int db = 0; db < 8; ++db) oacc[db][mq] *= fac;
                }
            }
#pragma unroll
            for (int nk = 0; nk < 2; ++nk)
#pragma unroll
                for (int mq = 0; mq < 2; ++mq)
#pragma unroll
                    for (int r = 0; r < 4; ++r)
                        pv[nk][mq][r] = exp2f(pv[nk][mq][r] - m_[mq]);
            // ---- P fragment in-register (hw cvt_pk); K=32 -> single fragment
            union { bf16x8 v; __hip_bfloat162 h[4]; } fp[2];
#pragma unroll
            for (int mq = 0; mq < 2; ++mq) {
                fp[mq].h[0] = __float22bfloat162_rn(
                    float2{pv[0][mq][0], pv[0][mq][1]});
                fp[mq].h[1] = __float22bfloat162_rn(
                    float2{pv[0][mq][2], pv[0][mq][3]});
                fp[mq].h[2] = __float22bfloat162_rn(
                    float2{pv[1][mq][0], pv[1][mq][1]});
                fp[mq].h[3] = __float22bfloat162_rn(
                    float2{pv[1][mq][2], pv[1][mq][3]});
            }
            // ---- PV: V b128 from [64][64] tile; O^T += V*P; l += 1*P
            __builtin_amdgcn_s_setprio(1);
#pragma unroll
            for (int db = 0; db < 8; ++db) {
                int r64 = (db & 3) * 16 + la;
                int slot = (((db >> 2) << 2) + lb) ^ (r64 & 7);
                bf16x8 fv = *(const bf16x8*)&Vsm[cur][r64 * 64 + slot * 8];
#pragma unroll
                for (int mq = 0; mq < 2; ++mq)
                    oacc[db][mq] = mfma16(fv, fp[mq].v, oacc[db][mq]);
            }
#pragma unroll
            for (int mq = 0; mq < 2; ++mq)
                lacc[mq] = mfma16(ones, fp[mq].v, lacc[mq]);
            __builtin_amdgcn_s_setprio(0);
        }
        SB0(); __builtin_amdgcn_s_barrier(); SB0();
        cur ^= 1;
    }
#undef STAGE_KV
#undef SB0

    // ---- normalize + store: d = db*16+lb*4+r, q = mq*16+la
#pragma unroll
    for (int mq = 0; mq < 2; ++mq) {
        float rl = 1.f / lacc[mq][0];
        int q = qw0 + mq * 16 + la;
#pragma unroll
        for (int db = 0; db < 8; ++db) {
            f32x4 o = oacc[db][mq];
            s16x4 pk;
#pragma unroll
            for (int r = 0; r < 4; ++r) pk[r] = (short)f2bf(o[r] * rl);
            int d = db * 16 + lb * 4;
            *(s16x4*)(Ow + (size_t)(b * S_ + q) * (NH_ * D_) + h * D_ + d) = pk;
        }
    }
}

extern "C" void kernel_launch(void* const* d_in, const int* in_sizes, int n_in,
                              void* d_out, int out_size, void* d_ws, size_t ws_size,
                              hipStream_t stream) {
    const float* hs   = (const float*)d_in[0];
    const float* cosT = (const float*)d_in[1];
    const float* sinT = (const float*)d_in[2];
    const float* Wq   = (const float*)d_in[3];
    const float* Wk   = (const float*)d_in[4];
    const float* Wv   = (const float*)d_in[5];
    const float* Wo   = (const float*)d_in[6];

    constexpr size_t Qn  = (size_t)B_ * S_ * NH_ * D_;    // 16.77M
    constexpr size_t Kn  = (size_t)B_ * S_ * NKV_ * D_;   // 4.19M
    constexpr size_t Hn  = (size_t)B_ * S_ * HID_;        // 16.77M
    constexpr size_t Wqn = (size_t)NH_ * D_ * HID_;       // 16.77M
    constexpr size_t Wkn = (size_t)NKV_ * D_ * HID_;      // 4.19M

    unsigned short* Qws   = (unsigned short*)d_ws;
    unsigned short* Kws   = Qws + Qn;
    unsigned short* Vtws  = Kws + Kn;
    unsigned short* AOws  = Vtws + Kn;
    unsigned short* hsb   = AOws + Qn;
    unsigned short* Wqkvb = hsb + Hn;                  // stacked (6144, 4096)
    unsigned short* Wob   = Wqkvb + Wqn + 2 * Wkn;
    constexpr size_t need = (Qn + 2 * Kn + Qn + Hn + Wqn + 2 * Wkn + Wqn) * 2;

    const int M = B_ * S_;
    dim3 blk(256);

    if (ws_size >= need) {
        // one merged cast launch: hs, Wq, Wk, Wv, Wo -> bf16
        cast_all_k<<<dim3(28672), blk, 0, stream>>>(
            hs, Wq, Wk, Wv, Wo,
            hsb, Wqkvb, Wqkvb + Wqn, Wqkvb + Wqn + Wkn, Wob);

        // Q = rope(hs @ Wq^T) * QSCALE  (grid 16x16 = 256, balanced)
        gemm256_k<1><<<dim3((M / 256) * (HID_ / 256)), dim3(512), 0, stream>>>(
            hsb, Wqkvb, nullptr, Qws, cosT, sinT, M, HID_, HID_);
        // K = rope(hs @ Wk^T), V^T(pi) = (hs @ Wv^T)^T  (grid 512 = 2/CU)
        gemm_kv_k<<<dim3((M / 128) * (2048 / 128)), dim3(512), 0, stream>>>(
            hsb, Wqkvb + Wqn, Kws, Vtws, cosT, sinT, M, HID_);
        // attention: 1024 blocks x 256 threads, 128 q-rows/block, 4 blocks/CU
        attn7_k<<<dim3(B_ * NH_ * (S_ / 128)), blk, 0, stream>>>(
            Qws, Kws, Vtws, AOws);
        // out = AO @ Wo^T (f32 epilogue)
        gemm256_k<0><<<dim3((M / 256) * (HID_ / 256)), dim3(512), 0, stream>>>(
            AOws, Wob, (float*)d_out, nullptr, nullptr, nullptr, M, HID_, NH_ * D_);
    } else {
        // fallback: fp32-staging GEMMs + attention
        unsigned short* Qf = (unsigned short*)d_ws;
        unsigned short* Kf = Qf + Qn;
        unsigned short* Vf = Kf + Kn;
        unsigned short* AOf = Vf + Kn;
        gemm_legacy_k<1, false><<<dim3((M / 128) * (NH_ * D_ / 128)), blk, 0, stream>>>(
            hs, Wq, Qf, cosT, sinT, M, NH_ * D_, HID_, QSCALE_);
        gemm_legacy_k<1, false><<<dim3((M / 128) * (NKV_ * D_ / 128)), blk, 0, stream>>>(
            hs, Wk, Kf, cosT, sinT, M, NKV_ * D_, HID_, 1.0f);
        gemm_legacy_k<3, false><<<dim3((M / 128) * (NKV_ * D_ / 128)), blk, 0, stream>>>(
            hs, Wv, Vf, nullptr, nullptr, M, NKV_ * D_, HID_, 0.f);
        attn7_k<<<dim3(B_ * NH_ * (S_ / 128)), blk, 0, stream>>>(
            Qf, Kf, Vf, AOf);
        gemm_legacy_k<0, true><<<dim3((M / 128) * (HID_ / 128)), blk, 0, stream>>>(
            AOf, Wo, (float*)d_out, nullptr, nullptr, M, HID_, NH_ * D_, 0.f);
    }
}

// Round 14
// 446.889 us; speedup vs baseline: 1.0538x; 1.0102x over previous
//
#include <hip/hip_runtime.h>
#include <hip/hip_bf16.h>

#define DEV __device__ __forceinline__

typedef __attribute__((ext_vector_type(8))) short bf16x8;
typedef __attribute__((ext_vector_type(4))) short s16x4;
typedef __attribute__((ext_vector_type(4))) float f32x4;

constexpr int B_ = 2, S_ = 2048, HID_ = 4096, NH_ = 32, NKV_ = 8, D_ = 128;
constexpr int GROUPS_ = NH_ / NKV_;
// fold 1/sqrt(D) and log2(e) into Q so attention uses exp2 directly
constexpr float QSCALE_ = 0.08838834764831845f * 1.4426950408889634f;

DEV unsigned short f2bf(float x) {
    union { float f; unsigned int u; } v; v.f = x;
    unsigned int r = v.u + 0x7fffu + ((v.u >> 16) & 1u);
    return (unsigned short)(r >> 16);
}

DEV f32x4 mfma16(bf16x8 a, bf16x8 b, f32x4 c) {
    return __builtin_amdgcn_mfma_f32_16x16x32_bf16(a, b, c, 0, 0, 0);
}

DEV void gll16(const void* g, void* l) {
    __builtin_amdgcn_global_load_lds(
        (const __attribute__((address_space(1))) unsigned int*)g,
        (__attribute__((address_space(3))) unsigned int*)l, 16, 0, 0);
}

// pi: permute s within 32-blocks so attn V b128 reads match the sigma k-slot
// mapping (sigma per 32-kv block: pos lb*8+m*4+r holds kv m*16+lb*4+r).
// 4-aligned-preserving: pi(s) = (s&~31)|((s>>2)&3)<<3|((s>>4)&1)<<2|(s&3)
DEV int vperm(int s) {
    return (s & ~31) | (((s >> 2) & 3) << 3) | (((s >> 4) & 1) << 2) | (s & 3);
}

// ---------------- merged fp32 -> bf16 cast (one launch, 5 segments) ----------
__global__ __launch_bounds__(256) void cast_all_k(
    const float* __restrict__ s0, const float* __restrict__ s1,
    const float* __restrict__ s2, const float* __restrict__ s3,
    const float* __restrict__ s4,
    unsigned short* __restrict__ d0, unsigned short* __restrict__ d1,
    unsigned short* __restrict__ d2, unsigned short* __restrict__ d3,
    unsigned short* __restrict__ d4)
{
    int bb = blockIdx.x;
    const float* s; unsigned short* d; int off;
    if      (bb < 8192)  { s = s0; d = d0; off = bb; }
    else if (bb < 16384) { s = s1; d = d1; off = bb - 8192; }
    else if (bb < 18432) { s = s2; d = d2; off = bb - 16384; }
    else if (bb < 20480) { s = s3; d = d3; off = bb - 18432; }
    else                 { s = s4; d = d4; off = bb - 20480; }
    size_t i = ((size_t)off * 256 + threadIdx.x) * 8;
    const f32x4* sp = (const f32x4*)(s + i);
    f32x4 a = sp[0], b = sp[1];
    bf16x8 o;
    o[0] = (short)f2bf(a[0]); o[1] = (short)f2bf(a[1]);
    o[2] = (short)f2bf(a[2]); o[3] = (short)f2bf(a[3]);
    o[4] = (short)f2bf(b[0]); o[5] = (short)f2bf(b[1]);
    o[6] = (short)f2bf(b[2]); o[7] = (short)f2bf(b[3]);
    *(bf16x8*)(d + i) = o;
}

// =============== 256x256 8-phase bf16 GEMM (T2+T3+T4+T5), C = A @ B^T ========
// EPI 0: f32 row-major store. EPI 1: Q RoPE epilogue (N=4096 launch).
// vmcnt ledger in INSTRUCTION units (each STAGE = 2 loads): prologue 8.
// P0 vmcnt(2) -> c0,c1,c2 complete; P2 vmcnt(4) -> c3 complete. Barriers only
// at P0/P2 (r9-proven: buf[nb] reads finished in tile t-1, ordered by P0).
template<int EPI>
__global__ __launch_bounds__(512, 2) void gemm256_k(
    const unsigned short* __restrict__ A, const unsigned short* __restrict__ Bw,
    float* __restrict__ Cf, unsigned short* __restrict__ Qo,
    const float* __restrict__ cosT, const float* __restrict__ sinT,
    int M, int N, int K)
{
    __shared__ __align__(16) unsigned short lds[65536];  // 128 KiB
    const int tid = threadIdx.x, lane = tid & 63;
    const int w = tid >> 6, wm = w >> 2, wn = w & 3;
    const int la = lane & 15, lb = lane >> 4;

    const int nwg = (int)gridDim.x;
    const int cpx = nwg >> 3;
    const int bid = (int)blockIdx.x;
    const int sw = (bid & 7) * cpx + (bid >> 3);
    const int ntn = N >> 8;
    const int bm = (sw / ntn) << 8, bn = (sw % ntn) << 8;

    const int srow = tid >> 3;                       // 0..63
    const int scol8 = (tid & 7) ^ (srow & 7);        // involution
    const size_t rK = (size_t)K;
    const unsigned short* gA = A + (size_t)(bm + srow) * rK + scol8 * 8;
    const unsigned short* gB = Bw + (size_t)(bn + srow) * rK + scol8 * 8;

#define STAGE_A_H0(buf, kt) { gll16(gA + (size_t)(kt),            &lds[(buf)*16384 + tid*8]); \
                              gll16(gA + (size_t)(kt) + 128*rK,   &lds[(buf)*16384 + 8192 + tid*8]); }
#define STAGE_A_H1(buf, kt) { gll16(gA + (size_t)(kt) + 64*rK,    &lds[(buf)*16384 + 4096 + tid*8]); \
                              gll16(gA + (size_t)(kt) + 192*rK,   &lds[(buf)*16384 + 12288 + tid*8]); }
#define STAGE_B_H0(buf, kt) { gll16(gB + (size_t)(kt),            &lds[32768 + (buf)*16384 + tid*8]); \
                              gll16(gB + (size_t)(kt) + 64*rK,    &lds[32768 + (buf)*16384 + 4096 + tid*8]); }
#define STAGE_B_H1(buf, kt) { gll16(gB + (size_t)(kt) + 128*rK,   &lds[32768 + (buf)*16384 + 8192 + tid*8]); \
                              gll16(gB + (size_t)(kt) + 192*rK,   &lds[32768 + (buf)*16384 + 12288 + tid*8]); }
#define SB0() __builtin_amdgcn_sched_barrier(0)

    f32x4 acc[8][4];
#pragma unroll
    for (int m = 0; m < 8; ++m)
#pragma unroll
        for (int j = 0; j < 4; ++j) acc[m][j] = f32x4{0.f, 0.f, 0.f, 0.f};

    auto rdA = [&](int buf, int m, int kk) -> bf16x8 {
        int r = wm * 128 + m * 16 + la;
        int slot = (kk * 4 + lb) ^ (la & 7);
        return *(const bf16x8*)&lds[buf * 16384 + r * 64 + slot * 8];
    };
    auto rdB = [&](int buf, int j, int kk) -> bf16x8 {
        int r = (wn + 4 * j) * 16 + la;
        int slot = (kk * 4 + lb) ^ (la & 7);
        return *(const bf16x8*)&lds[32768 + buf * 16384 + r * 64 + slot * 8];
    };

    STAGE_A_H0(0, 0); STAGE_B_H0(0, 0); STAGE_B_H1(0, 0); STAGE_A_H1(0, 0);

    bf16x8 af[4][2], b01[2][2], b23[2][2];
    int cur = 0;
    const int nt = K >> 6;
    for (int t = 0; t < nt; ++t) {
        const bool pre = (t + 1 < nt);
        const int kn = (t + 1) << 6;
        const int nb = cur ^ 1;
        // ---- P0: needs c0,c1 (vmcnt(2) confirms c0,c1,c2); barrier ----
        asm volatile("s_waitcnt vmcnt(2)" ::: "memory");
        SB0(); __builtin_amdgcn_s_barrier(); SB0();
#pragma unroll
        for (int m = 0; m < 4; ++m)
#pragma unroll
            for (int kk = 0; kk < 2; ++kk) af[m][kk] = rdA(cur, m, kk);
#pragma unroll
        for (int j = 0; j < 2; ++j)
#pragma unroll
            for (int kk = 0; kk < 2; ++kk) b01[j][kk] = rdB(cur, j, kk);
        if (pre) STAGE_A_H0(nb, kn);
        __builtin_amdgcn_s_setprio(1);
#pragma unroll
        for (int kk = 0; kk < 2; ++kk)
#pragma unroll
            for (int m = 0; m < 4; ++m)
#pragma unroll
                for (int j = 0; j < 2; ++j)
                    acc[m][j] = mfma16(af[m][kk], b01[j][kk], acc[m][j]);
        __builtin_amdgcn_s_setprio(0);
        // ---- P1: reads c2 (confirmed at P0); NO barrier needed ----
#pragma unroll
        for (int j = 0; j < 2; ++j)
#pragma unroll
            for (int kk = 0; kk < 2; ++kk) b23[j][kk] = rdB(cur, j + 2, kk);
        if (pre) STAGE_B_H0(nb, kn);
        __builtin_amdgcn_s_setprio(1);
#pragma unroll
        for (int kk = 0; kk < 2; ++kk)
#pragma unroll
            for (int m = 0; m < 4; ++m)
#pragma unroll
                for (int j = 0; j < 2; ++j)
                    acc[m][j + 2] = mfma16(af[m][kk], b23[j][kk], acc[m][j + 2]);
        __builtin_amdgcn_s_setprio(0);
        // ---- P2: needs c3 -> vmcnt(4) (c0',c1' remain); barrier ----
        if (pre) { asm volatile("s_waitcnt vmcnt(4)" ::: "memory"); }
        else     { asm volatile("s_waitcnt vmcnt(0)" ::: "memory"); }
        SB0(); __builtin_amdgcn_s_barrier(); SB0();
#pragma unroll
        for (int m = 0; m < 4; ++m)
#pragma unroll
            for (int kk = 0; kk < 2; ++kk) af[m][kk] = rdA(cur, m + 4, kk);
        if (pre) STAGE_B_H1(nb, kn);
        __builtin_amdgcn_s_setprio(1);
#pragma unroll
        for (int kk = 0; kk < 2; ++kk)
#pragma unroll
            for (int m = 0; m < 4; ++m)
#pragma unroll
                for (int j = 0; j < 2; ++j)
                    acc[m + 4][j + 2] = mfma16(af[m][kk], b23[j][kk], acc[m + 4][j + 2]);
        __builtin_amdgcn_s_setprio(0);
        // ---- P3: register-only MFMA; NO barrier needed ----
        if (pre) STAGE_A_H1(nb, kn);
        __builtin_amdgcn_s_setprio(1);
#pragma unroll
        for (int kk = 0; kk < 2; ++kk)
#pragma unroll
            for (int m = 0; m < 4; ++m)
#pragma unroll
                for (int j = 0; j < 2; ++j)
                    acc[m + 4][j] = mfma16(af[m][kk], b01[j][kk], acc[m + 4][j]);
        __builtin_amdgcn_s_setprio(0);
        cur ^= 1;
    }
#undef STAGE_A_H0
#undef STAGE_A_H1
#undef STAGE_B_H0
#undef STAGE_B_H1

    const int srow0 = bm + wm * 128;
    if constexpr (EPI == 0) {
#pragma unroll
        for (int m = 0; m < 8; ++m)
#pragma unroll
            for (int j = 0; j < 4; ++j) {
                int col = bn + (wn + 4 * j) * 16 + la;
#pragma unroll
                for (int r = 0; r < 4; ++r)
                    Cf[(size_t)(srow0 + m * 16 + lb * 4 + r) * N + col] = acc[m][j][r];
            }
    } else {
        // Q RoPE: j0/j1 = head hbase, j2/j3 = head hbase+1
        const int hbase = bn >> 7;
        const int d = wn * 16 + la;  // < 64; cos[d]==cos[d+64]
#pragma unroll
        for (int m = 0; m < 8; ++m) {
#pragma unroll
            for (int r = 0; r < 4; ++r) {
                int row = srow0 + m * 16 + lb * 4 + r;  // = b*S + s
                float cv = cosT[(size_t)row * D_ + d];
                float sv = sinT[(size_t)row * D_ + d];
#pragma unroll
                for (int p = 0; p < 2; ++p) {
                    float x1 = acc[m][p * 2 + 0][r], x2 = acc[m][p * 2 + 1][r];
                    unsigned short* o = Qo + (size_t)row * (NH_ * D_) + (hbase + p) * D_ + d;
                    o[0]  = f2bf((x1 * cv - x2 * sv) * QSCALE_);
                    o[64] = f2bf((x2 * cv + x1 * sv) * QSCALE_);
                }
            }
        }
    }
}

// =============== 128x128 2-phase bf16 GEMM for fused K+V (N=2048) ============
// r14 fix: __launch_bounds__(512,2) — the old (512,4) forced a 64-VGPR cap
// (r6/r10 failure mode); per-thread state is ~66, so the cap risked spills.
// LDS 64 KiB still admits 2 blocks/CU; occupancy unchanged.
__global__ __launch_bounds__(512, 2) void gemm_kv_k(
    const unsigned short* __restrict__ A, const unsigned short* __restrict__ Bw,
    unsigned short* __restrict__ Ko, unsigned short* __restrict__ Vo,
    const float* __restrict__ cosT, const float* __restrict__ sinT,
    int M, int K)
{
    __shared__ __align__(16) unsigned short lds[32768];  // 64 KiB
    const int tid = threadIdx.x, lane = tid & 63;
    const int w = tid >> 6, wm = w >> 2, wn = w & 3;
    const int la = lane & 15, lb = lane >> 4;

    const int nwg = (int)gridDim.x;           // 512
    const int cpx = nwg >> 3;
    const int bid = (int)blockIdx.x;
    const int sw = (bid & 7) * cpx + (bid >> 3);
    const int ntn = 2048 >> 7;                // 16
    const int bm = (sw / ntn) << 7, bn = (sw % ntn) << 7;

    const int srow = tid >> 3;
    const int scol8 = (tid & 7) ^ (srow & 7);
    const size_t rK = (size_t)K;
    const unsigned short* gA = A + (size_t)(bm + srow) * rK + scol8 * 8;
    const unsigned short* gB = Bw + (size_t)(bn + srow) * rK + scol8 * 8;

#define KV_STG_A(buf, kt)  { gll16(gA + (size_t)(kt),          &lds[(buf)*8192 + tid*8]); \
                             gll16(gA + (size_t)(kt) + 64*rK,  &lds[(buf)*8192 + 4096 + tid*8]); }
#define KV_STG_B0(buf, kt)   gll16(gB + (size_t)(kt),          &lds[16384 + (buf)*8192 + tid*8])
#define KV_STG_B1(buf, kt)   gll16(gB + (size_t)(kt) + 64*rK,  &lds[16384 + (buf)*8192 + 4096 + tid*8])
#define SB0() __builtin_amdgcn_sched_barrier(0)

    f32x4 acc[4][2];
#pragma unroll
    for (int m = 0; m < 4; ++m)
#pragma unroll
        for (int j = 0; j < 2; ++j) acc[m][j] = f32x4{0.f, 0.f, 0.f, 0.f};

    auto rdA = [&](int buf, int m, int kk) -> bf16x8 {
        int r = wm * 64 + m * 16 + la;
        int slot = (kk * 4 + lb) ^ (la & 7);
        return *(const bf16x8*)&lds[buf * 8192 + r * 64 + slot * 8];
    };
    auto rdB = [&](int buf, int j, int kk) -> bf16x8 {
        int r = (wn + 4 * j) * 16 + la;
        int slot = (kk * 4 + lb) ^ (la & 7);
        return *(const bf16x8*)&lds[16384 + buf * 8192 + r * 64 + slot * 8];
    };

    KV_STG_A(0, 0); KV_STG_B0(0, 0); KV_STG_B1(0, 0);

    bf16x8 af[4][2], bf0[2], bf1[2];
    int cur = 0;
    const int nt = K >> 6;
    for (int t = 0; t < nt; ++t) {
        const bool pre = (t + 1 < nt);
        const int kn = (t + 1) << 6;
        const int nb = cur ^ 1;
        asm volatile("s_waitcnt vmcnt(1)" ::: "memory");
        SB0(); __builtin_amdgcn_s_barrier(); SB0();
#pragma unroll
        for (int m = 0; m < 4; ++m)
#pragma unroll
            for (int kk = 0; kk < 2; ++kk) af[m][kk] = rdA(cur, m, kk);
#pragma unroll
        for (int kk = 0; kk < 2; ++kk) bf0[kk] = rdB(cur, 0, kk);
        if (pre) { KV_STG_A(nb, kn); KV_STG_B0(nb, kn); }
        __builtin_amdgcn_s_setprio(1);
#pragma unroll
        for (int kk = 0; kk < 2; ++kk)
#pragma unroll
            for (int m = 0; m < 4; ++m)
                acc[m][0] = mfma16(af[m][kk], bf0[kk], acc[m][0]);
        __builtin_amdgcn_s_setprio(0);
        if (pre) { asm volatile("s_waitcnt vmcnt(3)" ::: "memory"); }
        else     { asm volatile("s_waitcnt vmcnt(0)" ::: "memory"); }
        SB0(); __builtin_amdgcn_s_barrier(); SB0();
#pragma unroll
        for (int kk = 0; kk < 2; ++kk) bf1[kk] = rdB(cur, 1, kk);
        if (pre) KV_STG_B1(nb, kn);
        __builtin_amdgcn_s_setprio(1);
#pragma unroll
        for (int kk = 0; kk < 2; ++kk)
#pragma unroll
            for (int m = 0; m < 4; ++m)
                acc[m][1] = mfma16(af[m][kk], bf1[kk], acc[m][1]);
        __builtin_amdgcn_s_setprio(0);
        cur ^= 1;
    }
#undef KV_STG_A
#undef KV_STG_B0
#undef KV_STG_B1
#undef SB0

    const int rbase = bm + wm * 64;
    if (bn < 1024) {
        const int hbase = bn >> 7;
        const int d = wn * 16 + la;  // < 64
#pragma unroll
        for (int m = 0; m < 4; ++m)
#pragma unroll
            for (int r = 0; r < 4; ++r) {
                int row = rbase + m * 16 + lb * 4 + r;  // = b*S + s
                float cv = cosT[(size_t)row * D_ + d];
                float sv = sinT[(size_t)row * D_ + d];
                float x1 = acc[m][0][r], x2 = acc[m][1][r];
                unsigned short* o = Ko + (size_t)row * (NKV_ * D_) + hbase * D_ + d;
                o[0]  = f2bf(x1 * cv - x2 * sv);
                o[64] = f2bf(x2 * cv + x1 * sv);
            }
    } else {
        // V^T (B,NKV,D,S) with pi-permuted S (4-aligned rows: s%4==0)
        const int kv = (bn - 1024) >> 7;
#pragma unroll
        for (int m = 0; m < 4; ++m) {
            int row = rbase + m * 16 + lb * 4;
            int b = row >> 11, s = row & (S_ - 1);
            int sp = vperm(s);
#pragma unroll
            for (int j = 0; j < 2; ++j) {
                int d = (wn + 4 * j) * 16 + la;
                s16x4 pk;
#pragma unroll
                for (int r = 0; r < 4; ++r) pk[r] = (short)f2bf(acc[m][j][r]);
                *(s16x4*)&Vo[((size_t)(b * NKV_ + kv) * D_ + d) * S_ + sp] = pk;
            }
        }
    }
}

// ---------------- legacy fp32-input GEMM (ws fallback) -----------------------
template<int EPI, bool ABF16>
__global__ __launch_bounds__(256) void gemm_legacy_k(
    const void* __restrict__ Ap, const float* __restrict__ Bp,
    void* __restrict__ Cp, const float* __restrict__ cosT,
    const float* __restrict__ sinT, int M, int N, int K, float scale)
{
    constexpr int LDT = 40;
    __shared__ __align__(16) unsigned short Asm[128 * LDT];
    __shared__ __align__(16) unsigned short Bsm[128 * LDT];
    const int tid = threadIdx.x;
    const int lane = tid & 63;
    const int w = tid >> 6;
    const int la = lane & 15, lb = lane >> 4;
    const int ntn = N >> 7;
    const int bm = (int)(blockIdx.x / ntn) << 7;
    const int bn = (int)(blockIdx.x % ntn) << 7;

    f32x4 acc[2][8];
#pragma unroll
    for (int i = 0; i < 2; ++i)
#pragma unroll
        for (int j = 0; j < 8; ++j) acc[i][j] = f32x4{0.f, 0.f, 0.f, 0.f};

    for (int kt = 0; kt < K; kt += 32) {
        if constexpr (!ABF16) {
#pragma unroll
            for (int it = 0; it < 4; ++it) {
                int idx = it * 256 + tid;
                int r = idx >> 3, c = (idx & 7) << 2;
                const float* g = (const float*)Ap + (size_t)(bm + r) * K + kt + c;
                f32x4 v = *(const f32x4*)g;
                union { unsigned long long q; unsigned short u[4]; } pk;
                pk.u[0] = f2bf(v[0]); pk.u[1] = f2bf(v[1]);
                pk.u[2] = f2bf(v[2]); pk.u[3] = f2bf(v[3]);
                *(unsigned long long*)&Asm[r * LDT + c] = pk.q;
            }
        } else {
#pragma unroll
            for (int it = 0; it < 2; ++it) {
                int idx = it * 256 + tid;
                int r = idx >> 2, c = (idx & 3) << 3;
                const unsigned short* g =
                    (const unsigned short*)Ap + (size_t)(bm + r) * K + kt + c;
                *(bf16x8*)&Asm[r * LDT + c] = *(const bf16x8*)g;
            }
        }
#pragma unroll
        for (int it = 0; it < 4; ++it) {
            int idx = it * 256 + tid;
            int r = idx >> 3, c = (idx & 7) << 2;
            const float* g = Bp + (size_t)(bn + r) * K + kt + c;
            f32x4 v = *(const f32x4*)g;
            union { unsigned long long q; unsigned short u[4]; } pk;
            pk.u[0] = f2bf(v[0]); pk.u[1] = f2bf(v[1]);
            pk.u[2] = f2bf(v[2]); pk.u[3] = f2bf(v[3]);
            *(unsigned long long*)&Bsm[r * LDT + c] = pk.q;
        }
        __syncthreads();
        bf16x8 af0 = *(bf16x8*)&Asm[(w * 32 + la) * LDT + lb * 8];
        bf16x8 af1 = *(bf16x8*)&Asm[(w * 32 + 16 + la) * LDT + lb * 8];
#pragma unroll
        for (int nb = 0; nb < 8; ++nb) {
            bf16x8 bfr = *(bf16x8*)&Bsm[(nb * 16 + la) * LDT + lb * 8];
            acc[0][nb] = mfma16(af0, bfr, acc[0][nb]);
            acc[1][nb] = mfma16(af1, bfr, acc[1][nb]);
        }
        __syncthreads();
    }

    const int rbase = bm + w * 32;
    if constexpr (EPI == 0) {
        float* C = (float*)Cp;
#pragma unroll
        for (int mf = 0; mf < 2; ++mf)
#pragma unroll
            for (int nb = 0; nb < 8; ++nb)
#pragma unroll
                for (int r = 0; r < 4; ++r)
                    C[(size_t)(rbase + mf * 16 + lb * 4 + r) * N + bn + nb * 16 + la] =
                        acc[mf][nb][r];
    } else if constexpr (EPI == 1) {
        unsigned short* C = (unsigned short*)Cp;
#pragma unroll
        for (int mf = 0; mf < 2; ++mf) {
#pragma unroll
            for (int r = 0; r < 4; ++r) {
                int m = rbase + mf * 16 + lb * 4 + r;
                const float* cb = cosT + (size_t)m * D_;
                const float* sb = sinT + (size_t)m * D_;
#pragma unroll
                for (int nb = 0; nb < 4; ++nb) {
                    int d = nb * 16 + la;
                    float c = cb[d], s = sb[d];
                    float x1 = acc[mf][nb][r], x2 = acc[mf][nb + 4][r];
                    C[(size_t)m * N + bn + d]      = f2bf((x1 * c - x2 * s) * scale);
                    C[(size_t)m * N + bn + d + 64] = f2bf((x2 * c + x1 * s) * scale);
                }
            }
        }
    } else {
        unsigned short* C = (unsigned short*)Cp;
#pragma unroll
        for (int mf = 0; mf < 2; ++mf)
#pragma unroll
            for (int nb = 0; nb < 8; ++nb)
#pragma unroll
                for (int r = 0; r < 4; ++r) {
                    int m = rbase + mf * 16 + lb * 4 + r;
                    int b = m >> 11, s = m & (S_ - 1);
                    int n = bn + nb * 16 + la;
                    int kv = n >> 7, d = n & 127;
                    C[(((size_t)b * NKV_ + kv) * D_ + d) * S_ + vperm(s)] =
                        f2bf(acc[mf][nb][r]);
                }
    }
}

// ========== flash attention v7c: r13 structure + hoisted address math ========
// 4 waves x 32 q-rows = 128 q/block. KVBLK=32, 32 KiB dbuf LDS, (256,2).
// r14 change: all loop-invariant LDS read offsets (koff[4][2], voff[8]) and
// per-lane staging bases are precomputed OUTSIDE the KV loop — removes ~70
// VALU ops/tile of recomputed XOR-slot/address math from the critical path
// (r13: VALUBusy 51% at occ 26%).
__global__ __launch_bounds__(256, 2) void attn7_k(
    const unsigned short* __restrict__ Qw,  // (B,S,NH,D) bf16 * QSCALE
    const unsigned short* __restrict__ Kw,  // (B,S,NKV,D) bf16
    const unsigned short* __restrict__ Vt,  // (B,NKV,D,S-pi) bf16
    unsigned short* __restrict__ Ow)        // (B,S,NH*D) bf16
{
    __shared__ __align__(16) unsigned short Ksm[2][32 * 128];   // 2 x 8 KiB
    __shared__ __align__(16) unsigned short Vsm[2][64 * 64];    // 2 x 8 KiB
    const int tid = threadIdx.x, lane = tid & 63, w = tid >> 6;
    const int la = lane & 15, lb = lane >> 4;
    const int blk = blockIdx.x;
    const int g = blk >> 6;                       // 0..15
    const int qbi = (g < 8) ? (15 - g) : (g - 8); // heavy/light pairing
    const int bh = blk & 63;
    const int b = bh >> 5, h = bh & 31;
    const int kvh = h >> 2;
    const int qb = qbi * 128;
    const int qw0 = qb + w * 32;

    bf16x8 fq[2][4];
    const unsigned short* qp =
        Qw + ((size_t)(b * S_ + qw0 + la) * NH_ + h) * D_ + lb * 8;
#pragma unroll
    for (int mq = 0; mq < 2; ++mq)
#pragma unroll
        for (int kc = 0; kc < 4; ++kc)
            fq[mq][kc] = *(const bf16x8*)(qp + (size_t)mq * 16 * NH_ * D_ + kc * 32);

    bf16x8 ones;
#pragma unroll
    for (int i = 0; i < 8; ++i) ones[i] = (short)0x3F80;  // bf16 1.0

    float m_[2];
    f32x4 oacc[8][2], lacc[2];
    m_[0] = m_[1] = -__builtin_inff();
    lacc[0] = lacc[1] = f32x4{0.f, 0.f, 0.f, 0.f};
#pragma unroll
    for (int db = 0; db < 8; ++db)
#pragma unroll
        for (int mq = 0; mq < 2; ++mq) oacc[db][mq] = f32x4{0.f, 0.f, 0.f, 0.f};

    // ---- loop-invariant LDS read offsets (elements) ----
    int koff[4][2];
#pragma unroll
    for (int kc = 0; kc < 4; ++kc)
#pragma unroll
        for (int nk = 0; nk < 2; ++nk)
            koff[kc][nk] = (nk * 16 + la) * 128 + (((kc * 4 + lb) ^ (la & 7)) * 8);
    int voff[8];
#pragma unroll
    for (int db = 0; db < 8; ++db) {
        int r64 = (db & 3) * 16 + la;
        voff[db] = r64 * 64 + (((((db >> 2) << 2) + lb) ^ (r64 & 7)) * 8);
    }

    // ---- loop-invariant staging bases (per-lane global addresses) ----
    const int krb = tid >> 4, ksl = tid & 15;   // K: 16 rows/gll, 16 slots
    const int vrb = tid >> 3, vsl = tid & 7;    // V: 32 rows/gll, 8 slots
    const unsigned short* kbase = Kw + ((size_t)b * S_ * NKV_ + kvh) * D_;
    const unsigned short* vbase = Vt + ((size_t)(b * NKV_ + kvh) * D_) * S_;
    const unsigned short* kga[2];
    const unsigned short* vga[2];
#pragma unroll
    for (int it = 0; it < 2; ++it) {
        int row = it * 16 + krb;
        int cc = ksl ^ (row & 7);
        kga[it] = kbase + (size_t)row * (NKV_ * D_) + cc * 8;
        int vrow = it * 32 + vrb;
        int vc = vsl ^ (vrow & 7);
        int dg = ((vc >> 2) << 6) + vrow;
        vga[it] = vbase + (size_t)dg * S_ + (vc & 3) * 8;
    }

#define STAGE_KV(buf, kv0) {                                                   \
    _Pragma("unroll")                                                          \
    for (int it = 0; it < 2; ++it)                                             \
        gll16(kga[it] + (size_t)(kv0) * (NKV_ * D_),                           \
              &Ksm[buf][(it * 256 + tid) * 8]);                                \
    _Pragma("unroll")                                                          \
    for (int it = 0; it < 2; ++it)                                             \
        gll16(vga[it] + (kv0), &Vsm[buf][(it * 256 + tid) * 8]);               \
}
#define SB0() __builtin_amdgcn_sched_barrier(0)

    STAGE_KV(0, 0);
    int cur = 0;
    const int ntiles = (qb + 128) >> 5;
    for (int t = 0; t < ntiles; ++t) {
        const int kv0 = t << 5;
        const bool pre = (t + 1 < ntiles);
        if (pre) STAGE_KV(cur ^ 1, kv0 + 32);
        if (pre) { asm volatile("s_waitcnt vmcnt(4)" ::: "memory"); }
        else     { asm volatile("s_waitcnt vmcnt(0)" ::: "memory"); }
        SB0(); __builtin_amdgcn_s_barrier(); SB0();

        if (kv0 < qw0 + 32) {  // wave-uniform causal skip
            const unsigned short* kl = &Ksm[cur][0];
            const unsigned short* vl = &Vsm[cur][0];
            // ---- QK^T swapped: sacc[nk][mq], nk over 2 16-row k-blocks
            f32x4 sacc[2][2];
#pragma unroll
            for (int nk = 0; nk < 2; ++nk)
#pragma unroll
                for (int mq = 0; mq < 2; ++mq) sacc[nk][mq] = f32x4{0.f, 0.f, 0.f, 0.f};
            __builtin_amdgcn_s_setprio(1);
#pragma unroll
            for (int kc = 0; kc < 4; ++kc) {
#pragma unroll
                for (int nk = 0; nk < 2; ++nk) {
                    bf16x8 fk = *(const bf16x8*)&kl[koff[kc][nk]];
#pragma unroll
                    for (int mq = 0; mq < 2; ++mq)
                        sacc[nk][mq] = mfma16(fk, fq[mq][kc], sacc[nk][mq]);
                }
            }
            __builtin_amdgcn_s_setprio(0);
            // ---- mask + row max (k = kv0+nk*16+lb*4+r, q = qw0+mq*16+la)
            const bool diag = (kv0 + 31 > qw0);
            float pv[2][2][4];
            float pm[2];
#pragma unroll
            for (int mq = 0; mq < 2; ++mq) {
                int q = qw0 + mq * 16 + la;
                float mx = -__builtin_inff();
#pragma unroll
                for (int nk = 0; nk < 2; ++nk)
#pragma unroll
                    for (int r = 0; r < 4; ++r) {
                        float s = sacc[nk][mq][r];
                        if (diag) {
                            int k = kv0 + nk * 16 + lb * 4 + r;
                            s = (k <= q) ? s : -__builtin_inff();
                        }
                        pv[nk][mq][r] = s;
                        mx = fmaxf(mx, s);
                    }
                mx = fmaxf(mx, __shfl_xor(mx, 16));
                mx = fmaxf(mx, __shfl_xor(mx, 32));
                pm[mq] = mx;
            }
            // T13 defer-rescale (log2 domain, THR=8)
            const bool upd =
                __any((pm[0] > m_[0] + 8.f) || (pm[1] > m_[1] + 8.f));
            if (upd) {
#pragma unroll
                for (int mq = 0; mq < 2; ++mq) {
                    float mn = fmaxf(m_[mq], pm[mq]);
                    float fac = exp2f(m_[mq] - mn);
                    m_[mq] = mn;
                    lacc[mq] *= fac;
#pragma unroll
                    for (int db = 0; db < 8; ++db) oacc[db][mq] *= fac;
                }
            }
#pragma unroll
            for (int nk = 0; nk < 2; ++nk)
#pragma unroll
                for (int mq = 0; mq < 2; ++mq)
#pragma unroll
                    for (int r = 0; r < 4; ++r)
                        pv[nk][mq][r] = exp2f(pv[nk][mq][r] - m_[mq]);
            // ---- P fragment in-register (hw cvt_pk); K=32 -> single fragment
            union { bf16x8 v; __hip_bfloat162 h[4]; } fp[2];
#pragma unroll
            for (int mq = 0; mq < 2; ++mq) {
                fp[mq].h[0] = __float22bfloat162_rn(
                    float2{pv[0][mq][0], pv[0][mq][1]});
                fp[mq].h[1] = __float22bfloat162_rn(
                    float2{pv[0][mq][2], pv[0][mq][3]});
                fp[mq].h[2] = __float22bfloat162_rn(
                    float2{pv[1][mq][0], pv[1][mq][1]});
                fp[mq].h[3] = __float22bfloat162_rn(
                    float2{pv[1][mq][2], pv[1][mq][3]});
            }
            // ---- PV: V b128 from [64][64] tile; O^T += V*P; l += 1*P
            __builtin_amdgcn_s_setprio(1);
#pragma unroll
            for (int db = 0; db < 8; ++db) {
                bf16x8 fv = *(const bf16x8*)&vl[voff[db]];
#pragma unroll
                for (int mq = 0; mq < 2; ++mq)
                    oacc[db][mq] = mfma16(fv, fp[mq].v, oacc[db][mq]);
            }
#pragma unroll
            for (int mq = 0; mq < 2; ++mq)
                lacc[mq] = mfma16(ones, fp[mq].v, lacc[mq]);
            __builtin_amdgcn_s_setprio(0);
        }
        SB0(); __builtin_amdgcn_s_barrier(); SB0();
        cur ^= 1;
    }
#undef STAGE_KV
#undef SB0

    // ---- normalize + store: d = db*16+lb*4+r, q = mq*16+la
#pragma unroll
    for (int mq = 0; mq < 2; ++mq) {
        float rl = 1.f / lacc[mq][0];
        int q = qw0 + mq * 16 + la;
#pragma unroll
        for (int db = 0; db < 8; ++db) {
            f32x4 o = oacc[db][mq];
            s16x4 pk;
#pragma unroll
            for (int r = 0; r < 4; ++r) pk[r] = (short)f2bf(o[r] * rl);
            int d = db * 16 + lb * 4;
            *(s16x4*)(Ow + (size_t)(b * S_ + q) * (NH_ * D_) + h * D_ + d) = pk;
        }
    }
}

extern "C" void kernel_launch(void* const* d_in, const int* in_sizes, int n_in,
                              void* d_out, int out_size, void* d_ws, size_t ws_size,
                              hipStream_t stream) {
    const float* hs   = (const float*)d_in[0];
    const float* cosT = (const float*)d_in[1];
    const float* sinT = (const float*)d_in[2];
    const float* Wq   = (const float*)d_in[3];
    const float* Wk   = (const float*)d_in[4];
    const float* Wv   = (const float*)d_in[5];
    const float* Wo   = (const float*)d_in[6];

    constexpr size_t Qn  = (size_t)B_ * S_ * NH_ * D_;    // 16.77M
    constexpr size_t Kn  = (size_t)B_ * S_ * NKV_ * D_;   // 4.19M
    constexpr size_t Hn  = (size_t)B_ * S_ * HID_;        // 16.77M
    constexpr size_t Wqn = (size_t)NH_ * D_ * HID_;       // 16.77M
    constexpr size_t Wkn = (size_t)NKV_ * D_ * HID_;      // 4.19M

    unsigned short* Qws   = (unsigned short*)d_ws;
    unsigned short* Kws   = Qws + Qn;
    unsigned short* Vtws  = Kws + Kn;
    unsigned short* AOws  = Vtws + Kn;
    unsigned short* hsb   = AOws + Qn;
    unsigned short* Wqkvb = hsb + Hn;                  // stacked (6144, 4096)
    unsigned short* Wob   = Wqkvb + Wqn + 2 * Wkn;
    constexpr size_t need = (Qn + 2 * Kn + Qn + Hn + Wqn + 2 * Wkn + Wqn) * 2;

    const int M = B_ * S_;
    dim3 blk(256);

    if (ws_size >= need) {
        // one merged cast launch: hs, Wq, Wk, Wv, Wo -> bf16
        cast_all_k<<<dim3(28672), blk, 0, stream>>>(
            hs, Wq, Wk, Wv, Wo,
            hsb, Wqkvb, Wqkvb + Wqn, Wqkvb + Wqn + Wkn, Wob);

        // Q = rope(hs @ Wq^T) * QSCALE  (grid 16x16 = 256, balanced)
        gemm256_k<1><<<dim3((M / 256) * (HID_ / 256)), dim3(512), 0, stream>>>(
            hsb, Wqkvb, nullptr, Qws, cosT, sinT, M, HID_, HID_);
        // K = rope(hs @ Wk^T), V^T(pi) = (hs @ Wv^T)^T  (grid 512 = 2/CU)
        gemm_kv_k<<<dim3((M / 128) * (2048 / 128)), dim3(512), 0, stream>>>(
            hsb, Wqkvb + Wqn, Kws, Vtws, cosT, sinT, M, HID_);
        // attention: 1024 blocks x 256 threads, 128 q-rows/block, 4 blocks/CU
        attn7_k<<<dim3(B_ * NH_ * (S_ / 128)), blk, 0, stream>>>(
            Qws, Kws, Vtws, AOws);
        // out = AO @ Wo^T (f32 epilogue)
        gemm256_k<0><<<dim3((M / 256) * (HID_ / 256)), dim3(512), 0, stream>>>(
            AOws, Wob, (float*)d_out, nullptr, nullptr, nullptr, M, HID_, NH_ * D_);
    } else {
        // fallback: fp32-staging GEMMs + attention
        unsigned short* Qf = (unsigned short*)d_ws;
        unsigned short* Kf = Qf + Qn;
        unsigned short* Vf = Kf + Kn;
        unsigned short* AOf = Vf + Kn;
        gemm_legacy_k<1, false><<<dim3((M / 128) * (NH_ * D_ / 128)), blk, 0, stream>>>(
            hs, Wq, Qf, cosT, sinT, M, NH_ * D_, HID_, QSCALE_);
        gemm_legacy_k<1, false><<<dim3((M / 128) * (NKV_ * D_ / 128)), blk, 0, stream>>>(
            hs, Wk, Kf, cosT, sinT, M, NKV_ * D_, HID_, 1.0f);
        gemm_legacy_k<3, false><<<dim3((M / 128) * (NKV_ * D_ / 128)), blk, 0, stream>>>(
            hs, Wv, Vf, nullptr, nullptr, M, NKV_ * D_, HID_, 0.f);
        attn7_k<<<dim3(B_ * NH_ * (S_ / 128)), blk, 0, stream>>>(
            Qf, Kf, Vf, AOf);
        gemm_legacy_k<0, true><<<dim3((M / 128) * (HID_ / 128)), blk, 0, stream>>>(
            AOf, Wo, (float*)d_out, nullptr, nullptr, M, HID_, NH_ * D_, 0.f);
    }
}